// Round 4
// baseline (820.612 us; speedup 1.0000x reference)
//
#include <hip/hip_runtime.h>

// Problem constants (N=2048, L=512, K=16, DROP=2, DIM=1024)
#define NDIM 2048
#define LLEV 512
#define KDIM 16
#define HALF 1024

typedef __attribute__((ext_vector_type(8))) short bf16x8;   // 8 bf16 = 4 VGPRs
typedef __attribute__((ext_vector_type(4))) float f32x4;

// ---------------------------------------------------------------------------
// bf16 split helpers: x ~= hi + lo, each RNE bf16 (~16-17 mantissa bits total)
// ---------------------------------------------------------------------------
__device__ inline unsigned short f2bf(float x) {
    unsigned u = __float_as_uint(x);
    u += 0x7fffu + ((u >> 16) & 1u);
    return (unsigned short)(u >> 16);
}
__device__ inline float bf2f(unsigned short b) {
    return __uint_as_float(((unsigned)b) << 16);
}
__device__ inline void split2(float x, unsigned short& h, unsigned short& l) {
    h = f2bf(x);
    l = f2bf(x - bf2f(h));
}

__device__ inline void gl2lds16(const void* g, void* l) {
    __builtin_amdgcn_global_load_lds(
        (const __attribute__((address_space(1))) void*)g,
        (__attribute__((address_space(3))) void*)l, 16, 0, 0);
}

// ---------------------------------------------------------------------------
// compose_kernel: for each pair of levels (2t, 2t+1), build union support
// S_t (32 rows, padded with unused identity rows) and the dense 32x32
// combined operator W_t = U_{2t+1} U_{2t} restricted to S_t.
// One 64-thread block per pair; 256 blocks total.
// ---------------------------------------------------------------------------
__global__ __launch_bounds__(64) void compose_kernel(const float* __restrict__ O,
                                                     const int* __restrict__ idx,
                                                     int* __restrict__ Sarr,
                                                     float* __restrict__ Warr)
{
    __shared__ int s_S[32];
    __shared__ int s_pos[32];          // posA[0..16), posB[16..32)
    __shared__ float s_W[32][33];
    const int t = blockIdx.x;
    const int lane = threadIdx.x;
    const int* a = idx + (2 * t) * 16;       // sorted ascending, 16 distinct
    const int* b = idx + (2 * t + 1) * 16;   // sorted ascending, 16 distinct

    if (lane == 0) {
        // merge-dedup the two sorted lists
        int na = 0, i = 0, j = 0;
        while (i < 16 || j < 16) {
            int va = (i < 16) ? a[i] : 0x7fffffff;
            int vb = (j < 16) ? b[j] : 0x7fffffff;
            int v = va < vb ? va : vb;
            if (va == v) i++;
            if (vb == v) j++;
            s_S[na++] = v;
        }
        // pad to 32 with rows NOT in S (they get identity W rows)
        const int nm = na;
        int r = 0, p = 0;
        while (na < 32) {
            while (p < nm && s_S[p] < r) p++;
            if (p < nm && s_S[p] == r) { r++; continue; }
            s_S[na++] = r++;
        }
    }
    __syncthreads();
    if (lane < 32) {
        const int v = (lane < 16) ? a[lane] : b[lane - 16];
        int pp = 0;
        #pragma unroll
        for (int q = 0; q < 32; ++q) if (s_S[q] == v) pp = q;
        s_pos[lane] = pp;
        #pragma unroll
        for (int c = 0; c < 33; ++c) s_W[lane][c] = 0.f;
        s_W[lane][lane] = 1.f;
    }
    __syncthreads();
    // apply U_{2t} then U_{2t+1}: rows pos[j] <- sum_k O[j,k] * W[pos[k], :]
    const int j  = lane >> 2;
    const int cg = (lane & 3) * 8;
    #pragma unroll
    for (int step = 0; step < 2; ++step) {
        const float* Om = O + (size_t)(2 * t + step) * 256;
        float acc[8] = {};
        for (int k = 0; k < 16; ++k) {
            const float o = Om[j * 16 + k];
            const int p = s_pos[step * 16 + k];
            #pragma unroll
            for (int c = 0; c < 8; ++c) acc[c] += o * s_W[p][cg + c];
        }
        __syncthreads();   // all reads done
        const int pj = s_pos[step * 16 + j];
        #pragma unroll
        for (int c = 0; c < 8; ++c) s_W[pj][cg + c] = acc[c];
        __syncthreads();   // writes visible
    }
    // write out
    if (lane < 32) Sarr[t * 32 + lane] = s_S[lane];
    {
        const int r = lane >> 1, h0 = (lane & 1) * 16;
        float* wp = Warr + (size_t)t * 1024 + r * 32 + h0;
        #pragma unroll
        for (int c = 0; c < 16; ++c) wp[c] = s_W[r][h0 + c];
    }
}

// ---------------------------------------------------------------------------
// scan2_kernel: right = W_255 ... W_0 applied to identity, 8 columns/block,
// 256 blocks x 1 wave, barrier-free (single-wave lockstep ordering).
// 256 levels of dense 32x32 ops (vs 512 sparse 16-row levels) halves the
// serial latency chain; reads are same-address broadcasts; writeback uses a
// bit-2 XOR column swizzle to cut bank aliasing to ~4-way.
// ---------------------------------------------------------------------------
#define SOFF(r) ((((r) >> 2) & 1) * 4)
__global__ __launch_bounds__(64) void scan2_kernel(const float* __restrict__ Warr,
                                                   const int* __restrict__ Sarr,
                                                   float* __restrict__ right)
{
    __shared__ float slab[NDIM * 8];   // 64 KiB, col c of row r at r*8 + (c ^ SOFF(r))
    const int lane = threadIdx.x;
    const int c0 = blockIdx.x * 8;
    const int rr = lane & 31;          // out-row slot within S
    const int ch = (lane >> 5) * 4;    // column group 0 or 4

    for (int r = lane; r < NDIM; r += 64) {
        *(float4*)&slab[r * 8]     = make_float4(0.f, 0.f, 0.f, 0.f);
        *(float4*)&slab[r * 8 + 4] = make_float4(0.f, 0.f, 0.f, 0.f);
    }
    if (lane < 8) {
        const int r = c0 + lane;
        slab[r * 8 + (lane ^ SOFF(r))] = 1.0f;
    }

    // prefetch level 0: support S (all lanes) and this lane's W row
    int S[32]; float w[32];
    {
        const int4* sp = (const int4*)(Sarr);
        #pragma unroll
        for (int q = 0; q < 8; ++q) *(int4*)&S[q * 4] = sp[q];
        const float4* wp = (const float4*)(Warr + rr * 32);
        #pragma unroll
        for (int q = 0; q < 8; ++q) *(float4*)&w[q * 4] = wp[q];
    }

    for (int t = 0; t < 256; ++t) {
        int cs[32]; float cw[32];
        #pragma unroll
        for (int q = 0; q < 32; ++q) { cs[q] = S[q]; cw[q] = w[q]; }
        if (t + 1 < 256) {
            const int4* sp = (const int4*)(Sarr + (t + 1) * 32);
            #pragma unroll
            for (int q = 0; q < 8; ++q) *(int4*)&S[q * 4] = sp[q];
            const float4* wp = (const float4*)(Warr + (size_t)(t + 1) * 1024 + rr * 32);
            #pragma unroll
            for (int q = 0; q < 8; ++q) *(float4*)&w[q * 4] = wp[q];
        }
        float4 acc = make_float4(0.f, 0.f, 0.f, 0.f);
        #pragma unroll
        for (int k = 0; k < 32; ++k) {
            const int rk = cs[k];
            float4 v = *(const float4*)&slab[rk * 8 + (ch ^ SOFF(rk))];  // broadcast
            acc.x += cw[k] * v.x; acc.y += cw[k] * v.y;
            acc.z += cw[k] * v.z; acc.w += cw[k] * v.w;
        }
        const int ro = cs[rr];
        *(float4*)&slab[ro * 8 + (ch ^ SOFF(ro))] = acc;   // single-wave: ordered
    }

    for (int r0 = 0; r0 < NDIM; r0 += 32) {
        const int r = r0 + (lane >> 1);
        const int h = (lane & 1) * 4;
        *(float4*)(right + (size_t)r * NDIM + c0 + h) =
            *(float4*)&slab[r * 8 + (h ^ SOFF(r))];
    }
}

// ---------------------------------------------------------------------------
// Old scan (kept only for the fp32 fallback path)
// ---------------------------------------------------------------------------
__global__ __launch_bounds__(64) void scan_kernel(const float* __restrict__ O,
                                                  const int* __restrict__ idx,
                                                  float* __restrict__ right)
{
    __shared__ float slab[NDIM * 8];
    const int lane = threadIdx.x;
    const int c0 = blockIdx.x * 8;
    const int k  = lane >> 2;
    const int c2 = (lane & 3) * 2;

    for (int r = lane; r < NDIM; r += 64) {
        *(float4*)&slab[r * 8]     = make_float4(0.f, 0.f, 0.f, 0.f);
        *(float4*)&slab[r * 8 + 4] = make_float4(0.f, 0.f, 0.f, 0.f);
    }
    if (lane < 8) slab[(c0 + lane) * 8 + lane] = 1.0f;

    int rows[16]; float a[16]; int wrow;
    #pragma unroll
    for (int j = 0; j < 16; ++j) rows[j] = idx[j];
    {
        const float4* p4 = (const float4*)(O + k * 16);
        #pragma unroll
        for (int q = 0; q < 4; ++q) *(float4*)&a[q * 4] = p4[q];
    }
    wrow = idx[k];

    for (int l = 0; l < LLEV; ++l) {
        int rr[16]; float aa[16];
        const int wr = wrow;
        #pragma unroll
        for (int j = 0; j < 16; ++j) { rr[j] = rows[j]; aa[j] = a[j]; }
        if (l + 1 < LLEV) {
            const int* ip = idx + (l + 1) * 16;
            #pragma unroll
            for (int j = 0; j < 16; ++j) rows[j] = ip[j];
            const float4* p4 = (const float4*)(O + (l + 1) * 256 + k * 16);
            #pragma unroll
            for (int q = 0; q < 4; ++q) *(float4*)&a[q * 4] = p4[q];
            wrow = ip[k];
        }
        float sx = 0.f, sy = 0.f;
        #pragma unroll
        for (int j = 0; j < 16; ++j) {
            float2 v = *(float2*)&slab[rr[j] * 8 + c2];
            sx += aa[j] * v.x;
            sy += aa[j] * v.y;
        }
        *(float2*)&slab[wr * 8 + c2] = make_float2(sx, sy);
    }

    for (int r0 = 0; r0 < NDIM; r0 += 32) {
        const int r = r0 + (lane >> 1);
        const int h = (lane & 1) * 4;
        *(float4*)(right + (size_t)r * NDIM + c0 + h) = *(float4*)&slab[r * 8 + h];
    }
}

// ---------------------------------------------------------------------------
// Split-bf16 MFMA NT gemm: C[m,n] = sum_k A[m,k]*B[n,k] (both row-major)
// 3-pass: Ah*Bh + Ah*Bl + Al*Bh, fp32 accumulate. 128x128 tile, BK=64.
// ---------------------------------------------------------------------------
#define GBK 64
__global__ __launch_bounds__(256) void mfma_nt(const unsigned short* __restrict__ Ah,
                                               const unsigned short* __restrict__ Al,
                                               const unsigned short* __restrict__ Bh,
                                               const unsigned short* __restrict__ Bl,
                                               float* __restrict__ C,
                                               int M, int N, int K)
{
    __shared__ unsigned short sA_h[8 * 128 * 8];
    __shared__ unsigned short sA_l[8 * 128 * 8];
    __shared__ unsigned short sB_h[8 * 128 * 8];
    __shared__ unsigned short sB_l[8 * 128 * 8];

    const int tid  = threadIdx.x;
    const int wave = tid >> 6, lane = tid & 63;
    const int lm   = lane & 15, quad = lane >> 4;
    const int wm   = wave & 1,  wn   = wave >> 1;
    const int m0   = blockIdx.x * 128, n0 = blockIdx.y * 128;

    const unsigned short* gbase;
    unsigned short* sbase;
    if      (wave == 0) { gbase = Ah + (size_t)m0 * K; sbase = sA_h; }
    else if (wave == 1) { gbase = Al + (size_t)m0 * K; sbase = sA_l; }
    else if (wave == 2) { gbase = Bh + (size_t)n0 * K; sbase = sB_h; }
    else                { gbase = Bl + (size_t)n0 * K; sbase = sB_l; }

    f32x4 acc[4][4];
    #pragma unroll
    for (int i = 0; i < 4; ++i)
        #pragma unroll
        for (int j = 0; j < 4; ++j) acc[i][j] = (f32x4){0.f, 0.f, 0.f, 0.f};

    for (int k0 = 0; k0 < K; k0 += GBK) {
        #pragma unroll
        for (int h = 0; h < 2; ++h) {
            const unsigned short* gr = gbase + (size_t)(h * 64 + lane) * K + k0;
            unsigned short* sb = sbase + h * 512;
            #pragma unroll
            for (int c = 0; c < 8; ++c)
                gl2lds16(gr + c * 8, sb + c * 1024);
        }
        __syncthreads();
        #pragma unroll
        for (int sub = 0; sub < 2; ++sub) {
            const int co = (sub * 4 + quad) * 1024;
            bf16x8 ah[4], al[4], bh[4], bl[4];
            #pragma unroll
            for (int i = 0; i < 4; ++i) {
                const int m = wm * 64 + i * 16 + lm;
                ah[i] = *(const bf16x8*)&sA_h[co + m * 8];
                al[i] = *(const bf16x8*)&sA_l[co + m * 8];
            }
            #pragma unroll
            for (int j = 0; j < 4; ++j) {
                const int n = wn * 64 + j * 16 + lm;
                bh[j] = *(const bf16x8*)&sB_h[co + n * 8];
                bl[j] = *(const bf16x8*)&sB_l[co + n * 8];
            }
            #pragma unroll
            for (int i = 0; i < 4; ++i)
                #pragma unroll
                for (int j = 0; j < 4; ++j) {
                    acc[i][j] = __builtin_amdgcn_mfma_f32_16x16x32_bf16(ah[i], bh[j], acc[i][j], 0, 0, 0);
                    acc[i][j] = __builtin_amdgcn_mfma_f32_16x16x32_bf16(ah[i], bl[j], acc[i][j], 0, 0, 0);
                    acc[i][j] = __builtin_amdgcn_mfma_f32_16x16x32_bf16(al[i], bh[j], acc[i][j], 0, 0, 0);
                }
        }
        __syncthreads();
    }
    #pragma unroll
    for (int i = 0; i < 4; ++i) {
        const int mrow = m0 + wm * 64 + i * 16 + quad * 4;
        #pragma unroll
        for (int j = 0; j < 4; ++j) {
            float* cp = C + (size_t)mrow * N + n0 + wn * 64 + j * 16 + lm;
            #pragma unroll
            for (int r = 0; r < 4; ++r) cp[(size_t)r * N] = acc[i][j][r];
        }
    }
}

// ---------------------------------------------------------------------------
// fp32 -> bf16 hi/lo conversion (optional row gather). 4 floats/thread.
// ---------------------------------------------------------------------------
__global__ __launch_bounds__(256) void conv_hl(const float* __restrict__ src,
                                               const int* __restrict__ gidx,
                                               int kshift,
                                               unsigned short* __restrict__ h,
                                               unsigned short* __restrict__ l)
{
    const long e = ((long)blockIdx.x * 256 + threadIdx.x) * 4;
    const float* s;
    if (gidx) {
        const long row = e >> kshift;
        const long col = e - (row << kshift);
        s = src + ((size_t)gidx[row] << kshift) + col;
    } else {
        s = src + e;
    }
    float4 v = *(const float4*)s;
    ushort4 hh, ll;
    split2(v.x, hh.x, ll.x); split2(v.y, hh.y, ll.y);
    split2(v.z, hh.z, ll.z); split2(v.w, hh.w, ll.w);
    *(ushort4*)(h + e) = hh;
    *(ushort4*)(l + e) = ll;
}

// ---------------------------------------------------------------------------
// Transposing fp32 -> bf16 hi/lo: dst[k][m] = src[m][k]. 64x64 LDS tile.
// ---------------------------------------------------------------------------
__global__ __launch_bounds__(256) void tconv_hl(const float* __restrict__ src,
                                                int Msrc, int Ksrc,
                                                unsigned short* __restrict__ h,
                                                unsigned short* __restrict__ l)
{
    __shared__ float t[64][65];
    const int bi = blockIdx.x, bj = blockIdx.y;
    const int tx = threadIdx.x & 15, ty = threadIdx.x >> 4;
    #pragma unroll
    for (int r = 0; r < 4; ++r) {
        const int row = bi * 64 + ty + r * 16;
        float4 v = *(const float4*)(src + (size_t)row * Ksrc + bj * 64 + tx * 4);
        t[ty + r * 16][tx * 4 + 0] = v.x; t[ty + r * 16][tx * 4 + 1] = v.y;
        t[ty + r * 16][tx * 4 + 2] = v.z; t[ty + r * 16][tx * 4 + 3] = v.w;
    }
    __syncthreads();
    #pragma unroll
    for (int r = 0; r < 4; ++r) {
        const int drow = bj * 64 + ty + r * 16;
        ushort4 hh, ll;
        split2(t[tx * 4 + 0][ty + r * 16], hh.x, ll.x);
        split2(t[tx * 4 + 1][ty + r * 16], hh.y, ll.y);
        split2(t[tx * 4 + 2][ty + r * 16], hh.z, ll.z);
        split2(t[tx * 4 + 3][ty + r * 16], hh.w, ll.w);
        *(ushort4*)(h + (size_t)drow * Msrc + bi * 64 + tx * 4) = hh;
        *(ushort4*)(l + (size_t)drow * Msrc + bi * 64 + tx * 4) = ll;
    }
}

// ---------------------------------------------------------------------------
// GT[n,r] = Gfull[r,n] transposed+converted, Gfull fused on the fly:
//   Gfull[r,:] = active(r) ? W1[inva[r],:] : dmrow[r]*right[r,:]
// ---------------------------------------------------------------------------
__global__ __launch_bounds__(256) void gt_build(const float* __restrict__ W1,
                                                const float* __restrict__ right,
                                                const int* __restrict__ inva,
                                                const float* __restrict__ dmrow,
                                                unsigned short* __restrict__ h,
                                                unsigned short* __restrict__ l)
{
    __shared__ float t[64][65];
    const int bi = blockIdx.x, bj = blockIdx.y;
    const int tx = threadIdx.x & 15, ty = threadIdx.x >> 4;
    #pragma unroll
    for (int rr = 0; rr < 4; ++rr) {
        const int r = bi * 64 + ty + rr * 16;
        const int ia = inva[r];
        float4 v;
        if (ia >= 0) {
            v = *(const float4*)(W1 + (size_t)ia * NDIM + bj * 64 + tx * 4);
        } else {
            v = *(const float4*)(right + (size_t)r * NDIM + bj * 64 + tx * 4);
            const float s = dmrow[r];
            v.x *= s; v.y *= s; v.z *= s; v.w *= s;
        }
        t[ty + rr * 16][tx * 4 + 0] = v.x; t[ty + rr * 16][tx * 4 + 1] = v.y;
        t[ty + rr * 16][tx * 4 + 2] = v.z; t[ty + rr * 16][tx * 4 + 3] = v.w;
    }
    __syncthreads();
    #pragma unroll
    for (int rr = 0; rr < 4; ++rr) {
        const int drow = bj * 64 + ty + rr * 16;
        ushort4 hh, ll;
        split2(t[tx * 4 + 0][ty + rr * 16], hh.x, ll.x);
        split2(t[tx * 4 + 1][ty + rr * 16], hh.y, ll.y);
        split2(t[tx * 4 + 2][ty + rr * 16], hh.z, ll.z);
        split2(t[tx * 4 + 3][ty + rr * 16], hh.w, ll.w);
        *(ushort4*)(h + (size_t)drow * NDIM + bi * 64 + tx * 4) = hh;
        *(ushort4*)(l + (size_t)drow * NDIM + bi * 64 + tx * 4) = ll;
    }
}

// ---------------------------------------------------------------------------
// Small helpers
// ---------------------------------------------------------------------------
__global__ __launch_bounds__(256) void diag_kernel(const float* __restrict__ P,
                                                   const float* __restrict__ R,
                                                   float* __restrict__ diag_all)
{
    __shared__ float red[256];
    const int i = blockIdx.x;
    const float4* p4 = (const float4*)(P + (size_t)i * NDIM);
    const float4* r4 = (const float4*)(R + (size_t)i * NDIM);
    float s = 0.f;
    for (int kq = threadIdx.x; kq < NDIM / 4; kq += 256) {
        float4 a = p4[kq], b = r4[kq];
        s += a.x * b.x + a.y * b.y + a.z * b.z + a.w * b.w;
    }
    red[threadIdx.x] = s;
    __syncthreads();
    for (int off = 128; off > 0; off >>= 1) {
        if (threadIdx.x < off) red[threadIdx.x] += red[threadIdx.x + off];
        __syncthreads();
    }
    if (threadIdx.x == 0) diag_all[i] = red[0];
}

__global__ void prep2_kernel(const int* __restrict__ act, const int* __restrict__ inact,
                             const float* __restrict__ diag_all,
                             int* __restrict__ inva, float* __restrict__ dm,
                             float* __restrict__ dmrow)
{
    const int t = threadIdx.x;
    inva[t] = -1;
    inva[t + HALF] = -1;
    __syncthreads();
    inva[act[t]] = t;
    const int ir = inact[t];
    const float dv = diag_all[ir];
    dm[t] = dv;
    dmrow[ir] = dv;
}

__global__ __launch_bounds__(256) void build_D(const float* __restrict__ Daa,
                                               const float* __restrict__ diag_all,
                                               const int* __restrict__ inva,
                                               float* __restrict__ D)
{
    const int e = blockIdx.x * 256 + threadIdx.x;
    const int i = e >> 11, j = e & (NDIM - 1);
    const int ii = inva[i], jj = inva[j];
    float v = 0.f;
    if (ii >= 0 && jj >= 0) v = Daa[ii * HALF + jj];
    if (i == j) v = diag_all[i];
    D[e] = v;
}

__global__ __launch_bounds__(256) void mc_kernel(const float* __restrict__ dm,
                                                 float* __restrict__ mc)
{
    const int e = blockIdx.x * 256 + threadIdx.x;
    const int t = e >> 10, s = e & (HALF - 1);
    mc[e] = (t == s) ? dm[t] : 0.f;
}

__global__ __launch_bounds__(512) void gather_rows(const float* __restrict__ R,
                                                   const int* __restrict__ ridx,
                                                   float* __restrict__ outp)
{
    const int r = blockIdx.x;
    const int c = threadIdx.x * 4;
    *(float4*)(outp + (size_t)r * NDIM + c) =
        *(const float4*)(R + (size_t)ridx[r] * NDIM + c);
}

// ---------------------------------------------------------------------------
// fp32 fallback gemms (used only if ws_size is too small for bf16 scratch)
// ---------------------------------------------------------------------------
__global__ __launch_bounds__(256) void gemm_nt64(const float* __restrict__ A, int lda,
                                                 const int* __restrict__ ridxA,
                                                 const float* __restrict__ B, int ldb,
                                                 const int* __restrict__ ridxB,
                                                 float* __restrict__ C, int ldc, int Kk)
{
    __shared__ float As[16][68];
    __shared__ float Bs[16][68];
    const int tid = threadIdx.x;
    const int tx = tid & 15, ty = tid >> 4;
    const int m0 = blockIdx.x * 64, n0 = blockIdx.y * 64;
    const int li = tid >> 2;
    const int lk = (tid & 3) * 4;
    int rowA = m0 + li; if (ridxA) rowA = ridxA[rowA];
    int rowB = n0 + li; if (ridxB) rowB = ridxB[rowB];
    const float* pA = A + (size_t)rowA * lda + lk;
    const float* pB = B + (size_t)rowB * ldb + lk;
    float acc[4][4] = {};
    for (int k0 = 0; k0 < Kk; k0 += 16) {
        float4 a4 = *(const float4*)(pA + k0);
        float4 b4 = *(const float4*)(pB + k0);
        As[lk + 0][li] = a4.x; As[lk + 1][li] = a4.y; As[lk + 2][li] = a4.z; As[lk + 3][li] = a4.w;
        Bs[lk + 0][li] = b4.x; Bs[lk + 1][li] = b4.y; Bs[lk + 2][li] = b4.z; Bs[lk + 3][li] = b4.w;
        __syncthreads();
        #pragma unroll
        for (int kk = 0; kk < 16; ++kk) {
            float4 av = *(const float4*)&As[kk][ty * 4];
            float4 bv = *(const float4*)&Bs[kk][tx * 4];
            float a[4] = {av.x, av.y, av.z, av.w};
            float b[4] = {bv.x, bv.y, bv.z, bv.w};
            #pragma unroll
            for (int i = 0; i < 4; ++i)
                #pragma unroll
                for (int j = 0; j < 4; ++j) acc[i][j] += a[i] * b[j];
        }
        __syncthreads();
    }
    #pragma unroll
    for (int i = 0; i < 4; ++i) {
        float4 v = make_float4(acc[i][0], acc[i][1], acc[i][2], acc[i][3]);
        *(float4*)(C + (size_t)(m0 + ty * 4 + i) * ldc + n0 + tx * 4) = v;
    }
}

__global__ __launch_bounds__(256) void gemm_nn64(const float* __restrict__ A, int lda,
                                                 const float* __restrict__ B, int ldb,
                                                 float* __restrict__ C, int ldc, int Kk)
{
    __shared__ float As[16][68];
    __shared__ float Bs[16][68];
    const int tid = threadIdx.x;
    const int tx = tid & 15, ty = tid >> 4;
    const int m0 = blockIdx.x * 64, n0 = blockIdx.y * 64;
    const int li = tid >> 2;
    const int lk = (tid & 3) * 4;
    const int bk = tid >> 4;
    const int bn = (tid & 15) * 4;
    const float* pA = A + (size_t)(m0 + li) * lda + lk;
    float acc[4][4] = {};
    for (int k0 = 0; k0 < Kk; k0 += 16) {
        float4 a4 = *(const float4*)(pA + k0);
        float4 b4 = *(const float4*)(B + (size_t)(k0 + bk) * ldb + n0 + bn);
        As[lk + 0][li] = a4.x; As[lk + 1][li] = a4.y; As[lk + 2][li] = a4.z; As[lk + 3][li] = a4.w;
        *(float4*)&Bs[bk][bn] = b4;
        __syncthreads();
        #pragma unroll
        for (int kk = 0; kk < 16; ++kk) {
            float4 av = *(const float4*)&As[kk][ty * 4];
            float4 bv = *(const float4*)&Bs[kk][tx * 4];
            float a[4] = {av.x, av.y, av.z, av.w};
            float b[4] = {bv.x, bv.y, bv.z, bv.w};
            #pragma unroll
            for (int i = 0; i < 4; ++i)
                #pragma unroll
                for (int j = 0; j < 4; ++j) acc[i][j] += a[i] * b[j];
        }
        __syncthreads();
    }
    #pragma unroll
    for (int i = 0; i < 4; ++i) {
        float4 v = make_float4(acc[i][0], acc[i][1], acc[i][2], acc[i][3]);
        *(float4*)(C + (size_t)(m0 + ty * 4 + i) * ldc + n0 + tx * 4) = v;
    }
}

__global__ __launch_bounds__(256) void arec64(const float* __restrict__ fw,
                                              const float* __restrict__ mw,
                                              const float* __restrict__ W1,
                                              const float* __restrict__ dm,
                                              float* __restrict__ C)
{
    __shared__ float As[16][68];
    __shared__ float Bs[16][68];
    const int tid = threadIdx.x;
    const int tx = tid & 15, ty = tid >> 4;
    const int m0 = blockIdx.x * 64, n0 = blockIdx.y * 64;
    const int bk = tid >> 4;
    const int bn = (tid & 15) * 4;
    float acc[4][4] = {};
    for (int t0 = 0; t0 < NDIM; t0 += 16) {
        const int t = t0 + bk;
        const float* Hrow; const float* Grow; float gs;
        if (t < HALF) { Hrow = fw + (size_t)t * NDIM; Grow = W1 + (size_t)t * NDIM; gs = 1.f; }
        else          { Hrow = mw + (size_t)(t - HALF) * NDIM; Grow = Hrow; gs = dm[t - HALF]; }
        float4 a4 = *(const float4*)(Hrow + m0 + bn);
        float4 b4 = *(const float4*)(Grow + n0 + bn);
        b4.x *= gs; b4.y *= gs; b4.z *= gs; b4.w *= gs;
        *(float4*)&As[bk][bn] = a4;
        *(float4*)&Bs[bk][bn] = b4;
        __syncthreads();
        #pragma unroll
        for (int kk = 0; kk < 16; ++kk) {
            float4 av = *(const float4*)&As[kk][ty * 4];
            float4 bv = *(const float4*)&Bs[kk][tx * 4];
            float a[4] = {av.x, av.y, av.z, av.w};
            float b[4] = {bv.x, bv.y, bv.z, bv.w};
            #pragma unroll
            for (int i = 0; i < 4; ++i)
                #pragma unroll
                for (int j = 0; j < 4; ++j) acc[i][j] += a[i] * b[j];
        }
        __syncthreads();
    }
    #pragma unroll
    for (int i = 0; i < 4; ++i) {
        float4 v = make_float4(acc[i][0], acc[i][1], acc[i][2], acc[i][3]);
        *(float4*)(C + (size_t)(m0 + ty * 4 + i) * NDIM + n0 + tx * 4) = v;
    }
}

// ---------------------------------------------------------------------------
extern "C" void kernel_launch(void* const* d_in, const int* in_sizes, int n_in,
                              void* d_out, int out_size, void* d_ws, size_t ws_size,
                              hipStream_t stream)
{
    (void)in_sizes; (void)n_in; (void)out_size;
    const float* A     = (const float*)d_in[0];
    const float* O     = (const float*)d_in[1];
    const int*   idx   = (const int*)d_in[2];
    const int*   act   = (const int*)d_in[3];
    const int*   inact = (const int*)d_in[4];

    float* out = (float*)d_out;
    const size_t NN = (size_t)NDIM * NDIM;
    float* A_rec = out;                       // scratch for P = R@A until step 13
    float* right = out + NN;
    float* D     = out + 2 * NN;              // scratch for W1 until build_D
    float* mc    = out + 3 * NN;
    float* fc    = mc + (size_t)HALF * HALF;  // Daa
    float* mw    = fc + (size_t)HALF * HALF;
    float* fw    = mw + (size_t)HALF * NDIM;

    char*  w        = (char*)d_ws;
    float* diag_all = (float*)w;              // 2048 f
    float* dm       = (float*)(w + 8192);     // 1024 f
    int*   inva     = (int*)(w + 12288);      // 2048 i
    float* dmrow    = (float*)(w + 20480);    // 2048 f

    const size_t MB = 1024 * 1024;
    const size_t WS_NEEDED = 65536 + 32 * MB;

    if (ws_size >= WS_NEEDED) {
        // bf16 scratch regions
        char* r1 = w + 65536;                 // 16 MB: (Warr/Sarr) -> Rh/Rl -> RTh/RTl
        char* r2 = r1 + 16 * MB;              // 16 MB: Ah/Al -> Pa/F -> D/FT -> GT
        // Warr/Sarr live in r1 ONLY until scan2 completes (stream-ordered,
        // before conv_hl writes Rh there).
        float* Warr = (float*)r1;             // 1 MB
        int*   Sarr = (int*)(r1 + MB);        // 32 KB
        unsigned short* Rh  = (unsigned short*)r1;
        unsigned short* Rl  = (unsigned short*)(r1 + 8 * MB);
        unsigned short* RTh = Rh;
        unsigned short* RTl = Rl;
        unsigned short* Ah  = (unsigned short*)r2;
        unsigned short* Al  = (unsigned short*)(r2 + 8 * MB);
        unsigned short* Pah = (unsigned short*)r2;             // after P
        unsigned short* Pal = (unsigned short*)(r2 + 4 * MB);
        unsigned short* Fh  = (unsigned short*)(r2 + 8 * MB);
        unsigned short* Fl  = (unsigned short*)(r2 + 12 * MB);
        unsigned short* Dh  = (unsigned short*)r2;             // after Daa
        unsigned short* Dl  = (unsigned short*)(r2 + 2 * MB);
        unsigned short* FTh = (unsigned short*)(r2 + 4 * MB);
        unsigned short* FTl = (unsigned short*)(r2 + 8 * MB);
        unsigned short* GTh = (unsigned short*)r2;             // after W1
        unsigned short* GTl = (unsigned short*)(r2 + 8 * MB);

        // 1. pairwise level composition (parallel), then 256-level scan
        compose_kernel<<<256, 64, 0, stream>>>(O, idx, Sarr, Warr);
        scan2_kernel<<<256, 64, 0, stream>>>(Warr, Sarr, right);
        // 2. wavelets
        gather_rows<<<1024, 512, 0, stream>>>(right, act, fw);
        gather_rows<<<1024, 512, 0, stream>>>(right, inact, mw);
        // 3. convert R and A to bf16 hi/lo (overwrites Warr/Sarr — consumed)
        conv_hl<<<4096, 256, 0, stream>>>(right, nullptr, 11, Rh, Rl);
        conv_hl<<<4096, 256, 0, stream>>>(A, nullptr, 11, Ah, Al);
        // 4. P = R @ A (A symmetric -> NT)  [A_rec slot]
        mfma_nt<<<dim3(16, 16), 256, 0, stream>>>(Rh, Rl, Ah, Al, A_rec, NDIM, NDIM, NDIM);
        // 5. diag + prep
        diag_kernel<<<2048, 256, 0, stream>>>(A_rec, right, diag_all);
        prep2_kernel<<<1, 1024, 0, stream>>>(act, inact, diag_all, inva, dm, dmrow);
        // 7. Pa = P[act], F = fw in bf16
        conv_hl<<<2048, 256, 0, stream>>>(A_rec, act, 11, Pah, Pal);
        conv_hl<<<2048, 256, 0, stream>>>(fw, nullptr, 11, Fh, Fl);
        // 8. Daa = Pa . F^T  -> fc
        mfma_nt<<<dim3(8, 8), 256, 0, stream>>>(Pah, Pal, Fh, Fl, fc, HALF, HALF, NDIM);
        // 9. Dh/Dl = conv(Daa); FT = fw^T
        conv_hl<<<1024, 256, 0, stream>>>(fc, nullptr, 10, Dh, Dl);
        tconv_hl<<<dim3(16, 32), 256, 0, stream>>>(fw, HALF, NDIM, FTh, FTl);
        // 10. W1 = Daa @ fw  (NT on Daa rows x FT rows)  [D slot]
        mfma_nt<<<dim3(8, 16), 256, 0, stream>>>(Dh, Dl, FTh, FTl, D, HALF, NDIM, HALF);
        // 11. RT = right^T
        tconv_hl<<<dim3(32, 32), 256, 0, stream>>>(right, NDIM, NDIM, RTh, RTl);
        // 12. GT[n,r] = Gfull[r,n], Gfull fused from W1 / dm*right
        gt_build<<<dim3(32, 32), 256, 0, stream>>>(D, right, inva, dmrow, GTh, GTl);
        // 13. A_rec = RT . GT^T (= R^T Gfull)   [overwrites P]
        mfma_nt<<<dim3(16, 16), 256, 0, stream>>>(RTh, RTl, GTh, GTl, A_rec, NDIM, NDIM, NDIM);
        // 14. D output
        build_D<<<16384, 256, 0, stream>>>(fc, diag_all, inva, D);
        // 15. mother_coefficients = diag(dm)
        mc_kernel<<<4096, 256, 0, stream>>>(dm, mc);
    } else {
        // fp32 fallback (R1 structure)
        scan_kernel<<<256, 64, 0, stream>>>(O, idx, right);
        gather_rows<<<1024, 512, 0, stream>>>(right, act, fw);
        gather_rows<<<1024, 512, 0, stream>>>(right, inact, mw);
        gemm_nt64<<<dim3(32, 32), 256, 0, stream>>>(right, NDIM, nullptr, A, NDIM, nullptr,
                                                    A_rec, NDIM, NDIM);
        diag_kernel<<<2048, 256, 0, stream>>>(A_rec, right, diag_all);
        prep2_kernel<<<1, 1024, 0, stream>>>(act, inact, diag_all, inva, dm, dmrow);
        gemm_nt64<<<dim3(16, 16), 256, 0, stream>>>(A_rec, NDIM, act, right, NDIM, act,
                                                    fc, HALF, NDIM);
        gemm_nn64<<<dim3(16, 32), 256, 0, stream>>>(fc, HALF, fw, NDIM, D, NDIM, HALF);
        arec64<<<dim3(32, 32), 256, 0, stream>>>(fw, mw, D, dm, A_rec);
        build_D<<<16384, 256, 0, stream>>>(fc, diag_all, inva, D);
        mc_kernel<<<4096, 256, 0, stream>>>(dm, mc);
    }
}

// Round 5
// 686.750 us; speedup vs baseline: 1.1949x; 1.1949x over previous
//
#include <hip/hip_runtime.h>

// Problem constants (N=2048, L=512, K=16, DROP=2, DIM=1024)
#define NDIM 2048
#define LLEV 512
#define KDIM 16
#define HALF 1024

typedef __attribute__((ext_vector_type(8))) short bf16x8;   // 8 bf16 = 4 VGPRs
typedef __attribute__((ext_vector_type(4))) float f32x4;

// ---------------------------------------------------------------------------
// bf16 split helpers: x ~= hi + lo, each RNE bf16 (~16-17 mantissa bits total)
// ---------------------------------------------------------------------------
__device__ inline unsigned short f2bf(float x) {
    unsigned u = __float_as_uint(x);
    u += 0x7fffu + ((u >> 16) & 1u);
    return (unsigned short)(u >> 16);
}
__device__ inline float bf2f(unsigned short b) {
    return __uint_as_float(((unsigned)b) << 16);
}
__device__ inline void split2(float x, unsigned short& h, unsigned short& l) {
    h = f2bf(x);
    l = f2bf(x - bf2f(h));
}

__device__ inline void gl2lds16(const void* g, void* l) {
    __builtin_amdgcn_global_load_lds(
        (const __attribute__((address_space(1))) void*)g,
        (__attribute__((address_space(3))) void*)l, 16, 0, 0);
}

// ---------------------------------------------------------------------------
// compose_kernel: for each pair of levels (2t, 2t+1), build union support
// S_t (32 rows, padded with unused identity rows) and the dense 32x32
// combined operator W_t = U_{2t+1} U_{2t} restricted to S_t.
// One 64-thread block per pair; 256 blocks total. (Validated in R4.)
// ---------------------------------------------------------------------------
__global__ __launch_bounds__(64) void compose_kernel(const float* __restrict__ O,
                                                     const int* __restrict__ idx,
                                                     int* __restrict__ Sarr,
                                                     float* __restrict__ Warr)
{
    __shared__ int s_S[32];
    __shared__ int s_pos[32];          // posA[0..16), posB[16..32)
    __shared__ float s_W[32][33];
    const int t = blockIdx.x;
    const int lane = threadIdx.x;
    const int* a = idx + (2 * t) * 16;       // sorted ascending, 16 distinct
    const int* b = idx + (2 * t + 1) * 16;   // sorted ascending, 16 distinct

    if (lane == 0) {
        int na = 0, i = 0, j = 0;
        while (i < 16 || j < 16) {
            int va = (i < 16) ? a[i] : 0x7fffffff;
            int vb = (j < 16) ? b[j] : 0x7fffffff;
            int v = va < vb ? va : vb;
            if (va == v) i++;
            if (vb == v) j++;
            s_S[na++] = v;
        }
        const int nm = na;
        int r = 0, p = 0;
        while (na < 32) {
            while (p < nm && s_S[p] < r) p++;
            if (p < nm && s_S[p] == r) { r++; continue; }
            s_S[na++] = r++;
        }
    }
    __syncthreads();
    if (lane < 32) {
        const int v = (lane < 16) ? a[lane] : b[lane - 16];
        int pp = 0;
        #pragma unroll
        for (int q = 0; q < 32; ++q) if (s_S[q] == v) pp = q;
        s_pos[lane] = pp;
        #pragma unroll
        for (int c = 0; c < 33; ++c) s_W[lane][c] = 0.f;
        s_W[lane][lane] = 1.f;
    }
    __syncthreads();
    const int j  = lane >> 2;
    const int cg = (lane & 3) * 8;
    #pragma unroll
    for (int step = 0; step < 2; ++step) {
        const float* Om = O + (size_t)(2 * t + step) * 256;
        float acc[8] = {};
        for (int k = 0; k < 16; ++k) {
            const float o = Om[j * 16 + k];
            const int p = s_pos[step * 16 + k];
            #pragma unroll
            for (int c = 0; c < 8; ++c) acc[c] += o * s_W[p][cg + c];
        }
        __syncthreads();
        const int pj = s_pos[step * 16 + j];
        #pragma unroll
        for (int c = 0; c < 8; ++c) s_W[pj][cg + c] = acc[c];
        __syncthreads();
    }
    if (lane < 32) Sarr[t * 32 + lane] = s_S[lane];
    {
        const int r = lane >> 1, h0 = (lane & 1) * 16;
        float* wp = Warr + (size_t)t * 1024 + r * 32 + h0;
        #pragma unroll
        for (int c = 0; c < 16; ++c) wp[c] = s_W[r][h0 + c];
    }
}

// ---------------------------------------------------------------------------
// scan3_kernel: batch-2 scan with k-split lanes.
// 512 blocks x 64 lanes x 4 columns; slab 2048x4 fp32 = 32 KB (b128 aligned).
// lane = (rr = lane&31 -> out-row slot, ks = lane>>5 -> k-half).
// Per level: each lane loads 16 rows (b128 broadcast, 2 addrs/instr = free)
// + 16 coeffs, partial dot, shfl_xor(32) combine, lanes<32 write the row.
// Register budget ~80 (vs scan2's ~200) so loads pipeline; 256 chain links.
// Single-wave lockstep => no barriers.
// ---------------------------------------------------------------------------
__global__ __launch_bounds__(64) void scan3_kernel(const float* __restrict__ Warr,
                                                   const int* __restrict__ Sarr,
                                                   float* __restrict__ right)
{
    __shared__ float slab[NDIM * 4];   // 32 KiB: (r,c) at slab[r*4+c]
    const int lane = threadIdx.x;
    const int c0 = blockIdx.x * 4;
    const int rr = lane & 31;          // out-row slot within S
    const int ks = lane >> 5;          // k-half

    for (int r = lane; r < NDIM; r += 64)
        *(float4*)&slab[r * 4] = make_float4(0.f, 0.f, 0.f, 0.f);
    if (lane < 4) slab[(c0 + lane) * 4 + lane] = 1.0f;

    // prefetch level 0
    int rows[16]; float cf[16]; int wrow;
    {
        const int4* sp = (const int4*)(Sarr + ks * 16);
        #pragma unroll
        for (int q = 0; q < 4; ++q) *(int4*)&rows[q * 4] = sp[q];
        const float4* wp = (const float4*)(Warr + rr * 32 + ks * 16);
        #pragma unroll
        for (int q = 0; q < 4; ++q) *(float4*)&cf[q * 4] = wp[q];
        wrow = Sarr[rr];
    }

    for (int t = 0; t < 256; ++t) {
        int cr[16]; float cc[16];
        const int wr = wrow;
        #pragma unroll
        for (int q = 0; q < 16; ++q) { cr[q] = rows[q]; cc[q] = cf[q]; }
        // prefetch next level (overlaps the LDS chain below)
        if (t + 1 < 256) {
            const int4* sp = (const int4*)(Sarr + (t + 1) * 32 + ks * 16);
            #pragma unroll
            for (int q = 0; q < 4; ++q) *(int4*)&rows[q * 4] = sp[q];
            const float4* wp = (const float4*)(Warr + (size_t)(t + 1) * 1024 + rr * 32 + ks * 16);
            #pragma unroll
            for (int q = 0; q < 4; ++q) *(float4*)&cf[q * 4] = wp[q];
            wrow = Sarr[(t + 1) * 32 + rr];
        }
        // partial dot over this lane's 16 k's (broadcast b128 reads)
        float4 acc = make_float4(0.f, 0.f, 0.f, 0.f);
        #pragma unroll
        for (int j = 0; j < 16; ++j) {
            float4 v = *(const float4*)&slab[cr[j] * 4];
            acc.x += cc[j] * v.x; acc.y += cc[j] * v.y;
            acc.z += cc[j] * v.z; acc.w += cc[j] * v.w;
        }
        // combine k-halves across lane pairs (lane ^ 32)
        acc.x += __shfl_xor(acc.x, 32, 64);
        acc.y += __shfl_xor(acc.y, 32, 64);
        acc.z += __shfl_xor(acc.z, 32, 64);
        acc.w += __shfl_xor(acc.w, 32, 64);
        if (lane < 32)
            *(float4*)&slab[wr * 4] = acc;   // single-wave: program-ordered
    }

    #pragma unroll 4
    for (int i = 0; i < 32; ++i) {
        const int r = i * 64 + lane;
        *(float4*)(right + (size_t)r * NDIM + c0) = *(float4*)&slab[r * 4];
    }
}

// ---------------------------------------------------------------------------
// Old scan (kept only for the fp32 fallback path)
// ---------------------------------------------------------------------------
__global__ __launch_bounds__(64) void scan_kernel(const float* __restrict__ O,
                                                  const int* __restrict__ idx,
                                                  float* __restrict__ right)
{
    __shared__ float slab[NDIM * 8];
    const int lane = threadIdx.x;
    const int c0 = blockIdx.x * 8;
    const int k  = lane >> 2;
    const int c2 = (lane & 3) * 2;

    for (int r = lane; r < NDIM; r += 64) {
        *(float4*)&slab[r * 8]     = make_float4(0.f, 0.f, 0.f, 0.f);
        *(float4*)&slab[r * 8 + 4] = make_float4(0.f, 0.f, 0.f, 0.f);
    }
    if (lane < 8) slab[(c0 + lane) * 8 + lane] = 1.0f;

    int rows[16]; float a[16]; int wrow;
    #pragma unroll
    for (int j = 0; j < 16; ++j) rows[j] = idx[j];
    {
        const float4* p4 = (const float4*)(O + k * 16);
        #pragma unroll
        for (int q = 0; q < 4; ++q) *(float4*)&a[q * 4] = p4[q];
    }
    wrow = idx[k];

    for (int l = 0; l < LLEV; ++l) {
        int rr[16]; float aa[16];
        const int wr = wrow;
        #pragma unroll
        for (int j = 0; j < 16; ++j) { rr[j] = rows[j]; aa[j] = a[j]; }
        if (l + 1 < LLEV) {
            const int* ip = idx + (l + 1) * 16;
            #pragma unroll
            for (int j = 0; j < 16; ++j) rows[j] = ip[j];
            const float4* p4 = (const float4*)(O + (l + 1) * 256 + k * 16);
            #pragma unroll
            for (int q = 0; q < 4; ++q) *(float4*)&a[q * 4] = p4[q];
            wrow = ip[k];
        }
        float sx = 0.f, sy = 0.f;
        #pragma unroll
        for (int j = 0; j < 16; ++j) {
            float2 v = *(float2*)&slab[rr[j] * 8 + c2];
            sx += aa[j] * v.x;
            sy += aa[j] * v.y;
        }
        *(float2*)&slab[wr * 8 + c2] = make_float2(sx, sy);
    }

    for (int r0 = 0; r0 < NDIM; r0 += 32) {
        const int r = r0 + (lane >> 1);
        const int h = (lane & 1) * 4;
        *(float4*)(right + (size_t)r * NDIM + c0 + h) = *(float4*)&slab[r * 8 + h];
    }
}

// ---------------------------------------------------------------------------
// Split-bf16 MFMA NT gemm: C[m,n] = sum_k A[m,k]*B[n,k] (both row-major)
// 3-pass: Ah*Bh + Ah*Bl + Al*Bh, fp32 accumulate. 128x128 tile, BK=64.
// ---------------------------------------------------------------------------
#define GBK 64
__global__ __launch_bounds__(256) void mfma_nt(const unsigned short* __restrict__ Ah,
                                               const unsigned short* __restrict__ Al,
                                               const unsigned short* __restrict__ Bh,
                                               const unsigned short* __restrict__ Bl,
                                               float* __restrict__ C,
                                               int M, int N, int K)
{
    __shared__ unsigned short sA_h[8 * 128 * 8];
    __shared__ unsigned short sA_l[8 * 128 * 8];
    __shared__ unsigned short sB_h[8 * 128 * 8];
    __shared__ unsigned short sB_l[8 * 128 * 8];

    const int tid  = threadIdx.x;
    const int wave = tid >> 6, lane = tid & 63;
    const int lm   = lane & 15, quad = lane >> 4;
    const int wm   = wave & 1,  wn   = wave >> 1;
    const int m0   = blockIdx.x * 128, n0 = blockIdx.y * 128;

    const unsigned short* gbase;
    unsigned short* sbase;
    if      (wave == 0) { gbase = Ah + (size_t)m0 * K; sbase = sA_h; }
    else if (wave == 1) { gbase = Al + (size_t)m0 * K; sbase = sA_l; }
    else if (wave == 2) { gbase = Bh + (size_t)n0 * K; sbase = sB_h; }
    else                { gbase = Bl + (size_t)n0 * K; sbase = sB_l; }

    f32x4 acc[4][4];
    #pragma unroll
    for (int i = 0; i < 4; ++i)
        #pragma unroll
        for (int j = 0; j < 4; ++j) acc[i][j] = (f32x4){0.f, 0.f, 0.f, 0.f};

    for (int k0 = 0; k0 < K; k0 += GBK) {
        #pragma unroll
        for (int h = 0; h < 2; ++h) {
            const unsigned short* gr = gbase + (size_t)(h * 64 + lane) * K + k0;
            unsigned short* sb = sbase + h * 512;
            #pragma unroll
            for (int c = 0; c < 8; ++c)
                gl2lds16(gr + c * 8, sb + c * 1024);
        }
        __syncthreads();
        #pragma unroll
        for (int sub = 0; sub < 2; ++sub) {
            const int co = (sub * 4 + quad) * 1024;
            bf16x8 ah[4], al[4], bh[4], bl[4];
            #pragma unroll
            for (int i = 0; i < 4; ++i) {
                const int m = wm * 64 + i * 16 + lm;
                ah[i] = *(const bf16x8*)&sA_h[co + m * 8];
                al[i] = *(const bf16x8*)&sA_l[co + m * 8];
            }
            #pragma unroll
            for (int j = 0; j < 4; ++j) {
                const int n = wn * 64 + j * 16 + lm;
                bh[j] = *(const bf16x8*)&sB_h[co + n * 8];
                bl[j] = *(const bf16x8*)&sB_l[co + n * 8];
            }
            #pragma unroll
            for (int i = 0; i < 4; ++i)
                #pragma unroll
                for (int j = 0; j < 4; ++j) {
                    acc[i][j] = __builtin_amdgcn_mfma_f32_16x16x32_bf16(ah[i], bh[j], acc[i][j], 0, 0, 0);
                    acc[i][j] = __builtin_amdgcn_mfma_f32_16x16x32_bf16(ah[i], bl[j], acc[i][j], 0, 0, 0);
                    acc[i][j] = __builtin_amdgcn_mfma_f32_16x16x32_bf16(al[i], bh[j], acc[i][j], 0, 0, 0);
                }
        }
        __syncthreads();
    }
    #pragma unroll
    for (int i = 0; i < 4; ++i) {
        const int mrow = m0 + wm * 64 + i * 16 + quad * 4;
        #pragma unroll
        for (int j = 0; j < 4; ++j) {
            float* cp = C + (size_t)mrow * N + n0 + wn * 64 + j * 16 + lm;
            #pragma unroll
            for (int r = 0; r < 4; ++r) cp[(size_t)r * N] = acc[i][j][r];
        }
    }
}

// ---------------------------------------------------------------------------
// fp32 -> bf16 hi/lo conversion (optional row gather). 4 floats/thread.
// ---------------------------------------------------------------------------
__global__ __launch_bounds__(256) void conv_hl(const float* __restrict__ src,
                                               const int* __restrict__ gidx,
                                               int kshift,
                                               unsigned short* __restrict__ h,
                                               unsigned short* __restrict__ l)
{
    const long e = ((long)blockIdx.x * 256 + threadIdx.x) * 4;
    const float* s;
    if (gidx) {
        const long row = e >> kshift;
        const long col = e - (row << kshift);
        s = src + ((size_t)gidx[row] << kshift) + col;
    } else {
        s = src + e;
    }
    float4 v = *(const float4*)s;
    ushort4 hh, ll;
    split2(v.x, hh.x, ll.x); split2(v.y, hh.y, ll.y);
    split2(v.z, hh.z, ll.z); split2(v.w, hh.w, ll.w);
    *(ushort4*)(h + e) = hh;
    *(ushort4*)(l + e) = ll;
}

// ---------------------------------------------------------------------------
// Transposing fp32 -> bf16 hi/lo: dst[k][m] = src[m][k]. 64x64 LDS tile.
// ---------------------------------------------------------------------------
__global__ __launch_bounds__(256) void tconv_hl(const float* __restrict__ src,
                                                int Msrc, int Ksrc,
                                                unsigned short* __restrict__ h,
                                                unsigned short* __restrict__ l)
{
    __shared__ float t[64][65];
    const int bi = blockIdx.x, bj = blockIdx.y;
    const int tx = threadIdx.x & 15, ty = threadIdx.x >> 4;
    #pragma unroll
    for (int r = 0; r < 4; ++r) {
        const int row = bi * 64 + ty + r * 16;
        float4 v = *(const float4*)(src + (size_t)row * Ksrc + bj * 64 + tx * 4);
        t[ty + r * 16][tx * 4 + 0] = v.x; t[ty + r * 16][tx * 4 + 1] = v.y;
        t[ty + r * 16][tx * 4 + 2] = v.z; t[ty + r * 16][tx * 4 + 3] = v.w;
    }
    __syncthreads();
    #pragma unroll
    for (int r = 0; r < 4; ++r) {
        const int drow = bj * 64 + ty + r * 16;
        ushort4 hh, ll;
        split2(t[tx * 4 + 0][ty + r * 16], hh.x, ll.x);
        split2(t[tx * 4 + 1][ty + r * 16], hh.y, ll.y);
        split2(t[tx * 4 + 2][ty + r * 16], hh.z, ll.z);
        split2(t[tx * 4 + 3][ty + r * 16], hh.w, ll.w);
        *(ushort4*)(h + (size_t)drow * Msrc + bi * 64 + tx * 4) = hh;
        *(ushort4*)(l + (size_t)drow * Msrc + bi * 64 + tx * 4) = ll;
    }
}

// ---------------------------------------------------------------------------
// GT[n,r] = Gfull[r,n] transposed+converted, Gfull fused on the fly:
//   Gfull[r,:] = active(r) ? W1[inva[r],:] : dmrow[r]*right[r,:]
// ---------------------------------------------------------------------------
__global__ __launch_bounds__(256) void gt_build(const float* __restrict__ W1,
                                                const float* __restrict__ right,
                                                const int* __restrict__ inva,
                                                const float* __restrict__ dmrow,
                                                unsigned short* __restrict__ h,
                                                unsigned short* __restrict__ l)
{
    __shared__ float t[64][65];
    const int bi = blockIdx.x, bj = blockIdx.y;
    const int tx = threadIdx.x & 15, ty = threadIdx.x >> 4;
    #pragma unroll
    for (int rr = 0; rr < 4; ++rr) {
        const int r = bi * 64 + ty + rr * 16;
        const int ia = inva[r];
        float4 v;
        if (ia >= 0) {
            v = *(const float4*)(W1 + (size_t)ia * NDIM + bj * 64 + tx * 4);
        } else {
            v = *(const float4*)(right + (size_t)r * NDIM + bj * 64 + tx * 4);
            const float s = dmrow[r];
            v.x *= s; v.y *= s; v.z *= s; v.w *= s;
        }
        t[ty + rr * 16][tx * 4 + 0] = v.x; t[ty + rr * 16][tx * 4 + 1] = v.y;
        t[ty + rr * 16][tx * 4 + 2] = v.z; t[ty + rr * 16][tx * 4 + 3] = v.w;
    }
    __syncthreads();
    #pragma unroll
    for (int rr = 0; rr < 4; ++rr) {
        const int drow = bj * 64 + ty + rr * 16;
        ushort4 hh, ll;
        split2(t[tx * 4 + 0][ty + rr * 16], hh.x, ll.x);
        split2(t[tx * 4 + 1][ty + rr * 16], hh.y, ll.y);
        split2(t[tx * 4 + 2][ty + rr * 16], hh.z, ll.z);
        split2(t[tx * 4 + 3][ty + rr * 16], hh.w, ll.w);
        *(ushort4*)(h + (size_t)drow * NDIM + bi * 64 + tx * 4) = hh;
        *(ushort4*)(l + (size_t)drow * NDIM + bi * 64 + tx * 4) = ll;
    }
}

// ---------------------------------------------------------------------------
// Small helpers
// ---------------------------------------------------------------------------
__global__ __launch_bounds__(256) void diag_kernel(const float* __restrict__ P,
                                                   const float* __restrict__ R,
                                                   float* __restrict__ diag_all)
{
    __shared__ float red[256];
    const int i = blockIdx.x;
    const float4* p4 = (const float4*)(P + (size_t)i * NDIM);
    const float4* r4 = (const float4*)(R + (size_t)i * NDIM);
    float s = 0.f;
    for (int kq = threadIdx.x; kq < NDIM / 4; kq += 256) {
        float4 a = p4[kq], b = r4[kq];
        s += a.x * b.x + a.y * b.y + a.z * b.z + a.w * b.w;
    }
    red[threadIdx.x] = s;
    __syncthreads();
    for (int off = 128; off > 0; off >>= 1) {
        if (threadIdx.x < off) red[threadIdx.x] += red[threadIdx.x + off];
        __syncthreads();
    }
    if (threadIdx.x == 0) diag_all[i] = red[0];
}

__global__ void prep2_kernel(const int* __restrict__ act, const int* __restrict__ inact,
                             const float* __restrict__ diag_all,
                             int* __restrict__ inva, float* __restrict__ dm,
                             float* __restrict__ dmrow)
{
    const int t = threadIdx.x;
    inva[t] = -1;
    inva[t + HALF] = -1;
    __syncthreads();
    inva[act[t]] = t;
    const int ir = inact[t];
    const float dv = diag_all[ir];
    dm[t] = dv;
    dmrow[ir] = dv;
}

__global__ __launch_bounds__(256) void build_D(const float* __restrict__ Daa,
                                               const float* __restrict__ diag_all,
                                               const int* __restrict__ inva,
                                               float* __restrict__ D)
{
    const int e = blockIdx.x * 256 + threadIdx.x;
    const int i = e >> 11, j = e & (NDIM - 1);
    const int ii = inva[i], jj = inva[j];
    float v = 0.f;
    if (ii >= 0 && jj >= 0) v = Daa[ii * HALF + jj];
    if (i == j) v = diag_all[i];
    D[e] = v;
}

__global__ __launch_bounds__(256) void mc_kernel(const float* __restrict__ dm,
                                                 float* __restrict__ mc)
{
    const int e = blockIdx.x * 256 + threadIdx.x;
    const int t = e >> 10, s = e & (HALF - 1);
    mc[e] = (t == s) ? dm[t] : 0.f;
}

__global__ __launch_bounds__(512) void gather_rows(const float* __restrict__ R,
                                                   const int* __restrict__ ridx,
                                                   float* __restrict__ outp)
{
    const int r = blockIdx.x;
    const int c = threadIdx.x * 4;
    *(float4*)(outp + (size_t)r * NDIM + c) =
        *(const float4*)(R + (size_t)ridx[r] * NDIM + c);
}

// ---------------------------------------------------------------------------
// fp32 fallback gemms (used only if ws_size is too small for bf16 scratch)
// ---------------------------------------------------------------------------
__global__ __launch_bounds__(256) void gemm_nt64(const float* __restrict__ A, int lda,
                                                 const int* __restrict__ ridxA,
                                                 const float* __restrict__ B, int ldb,
                                                 const int* __restrict__ ridxB,
                                                 float* __restrict__ C, int ldc, int Kk)
{
    __shared__ float As[16][68];
    __shared__ float Bs[16][68];
    const int tid = threadIdx.x;
    const int tx = tid & 15, ty = tid >> 4;
    const int m0 = blockIdx.x * 64, n0 = blockIdx.y * 64;
    const int li = tid >> 2;
    const int lk = (tid & 3) * 4;
    int rowA = m0 + li; if (ridxA) rowA = ridxA[rowA];
    int rowB = n0 + li; if (ridxB) rowB = ridxB[rowB];
    const float* pA = A + (size_t)rowA * lda + lk;
    const float* pB = B + (size_t)rowB * ldb + lk;
    float acc[4][4] = {};
    for (int k0 = 0; k0 < Kk; k0 += 16) {
        float4 a4 = *(const float4*)(pA + k0);
        float4 b4 = *(const float4*)(pB + k0);
        As[lk + 0][li] = a4.x; As[lk + 1][li] = a4.y; As[lk + 2][li] = a4.z; As[lk + 3][li] = a4.w;
        Bs[lk + 0][li] = b4.x; Bs[lk + 1][li] = b4.y; Bs[lk + 2][li] = b4.z; Bs[lk + 3][li] = b4.w;
        __syncthreads();
        #pragma unroll
        for (int kk = 0; kk < 16; ++kk) {
            float4 av = *(const float4*)&As[kk][ty * 4];
            float4 bv = *(const float4*)&Bs[kk][tx * 4];
            float a[4] = {av.x, av.y, av.z, av.w};
            float b[4] = {bv.x, bv.y, bv.z, bv.w};
            #pragma unroll
            for (int i = 0; i < 4; ++i)
                #pragma unroll
                for (int j = 0; j < 4; ++j) acc[i][j] += a[i] * b[j];
        }
        __syncthreads();
    }
    #pragma unroll
    for (int i = 0; i < 4; ++i) {
        float4 v = make_float4(acc[i][0], acc[i][1], acc[i][2], acc[i][3]);
        *(float4*)(C + (size_t)(m0 + ty * 4 + i) * ldc + n0 + tx * 4) = v;
    }
}

__global__ __launch_bounds__(256) void gemm_nn64(const float* __restrict__ A, int lda,
                                                 const float* __restrict__ B, int ldb,
                                                 float* __restrict__ C, int ldc, int Kk)
{
    __shared__ float As[16][68];
    __shared__ float Bs[16][68];
    const int tid = threadIdx.x;
    const int tx = tid & 15, ty = tid >> 4;
    const int m0 = blockIdx.x * 64, n0 = blockIdx.y * 64;
    const int li = tid >> 2;
    const int lk = (tid & 3) * 4;
    const int bk = tid >> 4;
    const int bn = (tid & 15) * 4;
    const float* pA = A + (size_t)(m0 + li) * lda + lk;
    float acc[4][4] = {};
    for (int k0 = 0; k0 < Kk; k0 += 16) {
        float4 a4 = *(const float4*)(pA + k0);
        float4 b4 = *(const float4*)(B + (size_t)(k0 + bk) * ldb + n0 + bn);
        As[lk + 0][li] = a4.x; As[lk + 1][li] = a4.y; As[lk + 2][li] = a4.z; As[lk + 3][li] = a4.w;
        *(float4*)&Bs[bk][bn] = b4;
        __syncthreads();
        #pragma unroll
        for (int kk = 0; kk < 16; ++kk) {
            float4 av = *(const float4*)&As[kk][ty * 4];
            float4 bv = *(const float4*)&Bs[kk][tx * 4];
            float a[4] = {av.x, av.y, av.z, av.w};
            float b[4] = {bv.x, bv.y, bv.z, bv.w};
            #pragma unroll
            for (int i = 0; i < 4; ++i)
                #pragma unroll
                for (int j = 0; j < 4; ++j) acc[i][j] += a[i] * b[j];
        }
        __syncthreads();
    }
    #pragma unroll
    for (int i = 0; i < 4; ++i) {
        float4 v = make_float4(acc[i][0], acc[i][1], acc[i][2], acc[i][3]);
        *(float4*)(C + (size_t)(m0 + ty * 4 + i) * ldc + n0 + tx * 4) = v;
    }
}

__global__ __launch_bounds__(256) void arec64(const float* __restrict__ fw,
                                              const float* __restrict__ mw,
                                              const float* __restrict__ W1,
                                              const float* __restrict__ dm,
                                              float* __restrict__ C)
{
    __shared__ float As[16][68];
    __shared__ float Bs[16][68];
    const int tid = threadIdx.x;
    const int tx = tid & 15, ty = tid >> 4;
    const int m0 = blockIdx.x * 64, n0 = blockIdx.y * 64;
    const int bk = tid >> 4;
    const int bn = (tid & 15) * 4;
    float acc[4][4] = {};
    for (int t0 = 0; t0 < NDIM; t0 += 16) {
        const int t = t0 + bk;
        const float* Hrow; const float* Grow; float gs;
        if (t < HALF) { Hrow = fw + (size_t)t * NDIM; Grow = W1 + (size_t)t * NDIM; gs = 1.f; }
        else          { Hrow = mw + (size_t)(t - HALF) * NDIM; Grow = Hrow; gs = dm[t - HALF]; }
        float4 a4 = *(const float4*)(Hrow + m0 + bn);
        float4 b4 = *(const float4*)(Grow + n0 + bn);
        b4.x *= gs; b4.y *= gs; b4.z *= gs; b4.w *= gs;
        *(float4*)&As[bk][bn] = a4;
        *(float4*)&Bs[bk][bn] = b4;
        __syncthreads();
        #pragma unroll
        for (int kk = 0; kk < 16; ++kk) {
            float4 av = *(const float4*)&As[kk][ty * 4];
            float4 bv = *(const float4*)&Bs[kk][tx * 4];
            float a[4] = {av.x, av.y, av.z, av.w};
            float b[4] = {bv.x, bv.y, bv.z, bv.w};
            #pragma unroll
            for (int i = 0; i < 4; ++i)
                #pragma unroll
                for (int j = 0; j < 4; ++j) acc[i][j] += a[i] * b[j];
        }
        __syncthreads();
    }
    #pragma unroll
    for (int i = 0; i < 4; ++i) {
        float4 v = make_float4(acc[i][0], acc[i][1], acc[i][2], acc[i][3]);
        *(float4*)(C + (size_t)(m0 + ty * 4 + i) * NDIM + n0 + tx * 4) = v;
    }
}

// ---------------------------------------------------------------------------
extern "C" void kernel_launch(void* const* d_in, const int* in_sizes, int n_in,
                              void* d_out, int out_size, void* d_ws, size_t ws_size,
                              hipStream_t stream)
{
    (void)in_sizes; (void)n_in; (void)out_size;
    const float* A     = (const float*)d_in[0];
    const float* O     = (const float*)d_in[1];
    const int*   idx   = (const int*)d_in[2];
    const int*   act   = (const int*)d_in[3];
    const int*   inact = (const int*)d_in[4];

    float* out = (float*)d_out;
    const size_t NN = (size_t)NDIM * NDIM;
    float* A_rec = out;                       // scratch for P = R@A until step 13
    float* right = out + NN;
    float* D     = out + 2 * NN;              // scratch for W1 until build_D
    float* mc    = out + 3 * NN;
    float* fc    = mc + (size_t)HALF * HALF;  // Daa
    float* mw    = fc + (size_t)HALF * HALF;
    float* fw    = mw + (size_t)HALF * NDIM;

    char*  w        = (char*)d_ws;
    float* diag_all = (float*)w;              // 2048 f
    float* dm       = (float*)(w + 8192);     // 1024 f
    int*   inva     = (int*)(w + 12288);      // 2048 i
    float* dmrow    = (float*)(w + 20480);    // 2048 f

    const size_t MB = 1024 * 1024;
    const size_t WS_NEEDED = 65536 + 32 * MB;

    if (ws_size >= WS_NEEDED) {
        // bf16 scratch regions
        char* r1 = w + 65536;                 // 16 MB: (Warr/Sarr) -> Rh/Rl -> RTh/RTl
        char* r2 = r1 + 16 * MB;              // 16 MB: Ah/Al -> Pa/F -> D/FT -> GT
        // Warr/Sarr live in r1 ONLY until scan3 completes (stream-ordered,
        // before conv_hl writes Rh there).
        float* Warr = (float*)r1;             // 1 MB
        int*   Sarr = (int*)(r1 + MB);        // 32 KB
        unsigned short* Rh  = (unsigned short*)r1;
        unsigned short* Rl  = (unsigned short*)(r1 + 8 * MB);
        unsigned short* RTh = Rh;
        unsigned short* RTl = Rl;
        unsigned short* Ah  = (unsigned short*)r2;
        unsigned short* Al  = (unsigned short*)(r2 + 8 * MB);
        unsigned short* Pah = (unsigned short*)r2;             // after P
        unsigned short* Pal = (unsigned short*)(r2 + 4 * MB);
        unsigned short* Fh  = (unsigned short*)(r2 + 8 * MB);
        unsigned short* Fl  = (unsigned short*)(r2 + 12 * MB);
        unsigned short* Dh  = (unsigned short*)r2;             // after Daa
        unsigned short* Dl  = (unsigned short*)(r2 + 2 * MB);
        unsigned short* FTh = (unsigned short*)(r2 + 4 * MB);
        unsigned short* FTl = (unsigned short*)(r2 + 8 * MB);
        unsigned short* GTh = (unsigned short*)r2;             // after W1
        unsigned short* GTl = (unsigned short*)(r2 + 8 * MB);

        // 1. pairwise level composition (parallel), then 256-level k-split scan
        compose_kernel<<<256, 64, 0, stream>>>(O, idx, Sarr, Warr);
        scan3_kernel<<<512, 64, 0, stream>>>(Warr, Sarr, right);
        // 2. wavelets
        gather_rows<<<1024, 512, 0, stream>>>(right, act, fw);
        gather_rows<<<1024, 512, 0, stream>>>(right, inact, mw);
        // 3. convert R and A to bf16 hi/lo (overwrites Warr/Sarr — consumed)
        conv_hl<<<4096, 256, 0, stream>>>(right, nullptr, 11, Rh, Rl);
        conv_hl<<<4096, 256, 0, stream>>>(A, nullptr, 11, Ah, Al);
        // 4. P = R @ A (A symmetric -> NT)  [A_rec slot]
        mfma_nt<<<dim3(16, 16), 256, 0, stream>>>(Rh, Rl, Ah, Al, A_rec, NDIM, NDIM, NDIM);
        // 5. diag + prep
        diag_kernel<<<2048, 256, 0, stream>>>(A_rec, right, diag_all);
        prep2_kernel<<<1, 1024, 0, stream>>>(act, inact, diag_all, inva, dm, dmrow);
        // 7. Pa = P[act], F = fw in bf16
        conv_hl<<<2048, 256, 0, stream>>>(A_rec, act, 11, Pah, Pal);
        conv_hl<<<2048, 256, 0, stream>>>(fw, nullptr, 11, Fh, Fl);
        // 8. Daa = Pa . F^T  -> fc
        mfma_nt<<<dim3(8, 8), 256, 0, stream>>>(Pah, Pal, Fh, Fl, fc, HALF, HALF, NDIM);
        // 9. Dh/Dl = conv(Daa); FT = fw^T
        conv_hl<<<1024, 256, 0, stream>>>(fc, nullptr, 10, Dh, Dl);
        tconv_hl<<<dim3(16, 32), 256, 0, stream>>>(fw, HALF, NDIM, FTh, FTl);
        // 10. W1 = Daa @ fw  (NT on Daa rows x FT rows)  [D slot]
        mfma_nt<<<dim3(8, 16), 256, 0, stream>>>(Dh, Dl, FTh, FTl, D, HALF, NDIM, HALF);
        // 11. RT = right^T
        tconv_hl<<<dim3(32, 32), 256, 0, stream>>>(right, NDIM, NDIM, RTh, RTl);
        // 12. GT[n,r] = Gfull[r,n], Gfull fused from W1 / dm*right
        gt_build<<<dim3(32, 32), 256, 0, stream>>>(D, right, inva, dmrow, GTh, GTl);
        // 13. A_rec = RT . GT^T (= R^T Gfull)   [overwrites P]
        mfma_nt<<<dim3(16, 16), 256, 0, stream>>>(RTh, RTl, GTh, GTl, A_rec, NDIM, NDIM, NDIM);
        // 14. D output
        build_D<<<16384, 256, 0, stream>>>(fc, diag_all, inva, D);
        // 15. mother_coefficients = diag(dm)
        mc_kernel<<<4096, 256, 0, stream>>>(dm, mc);
    } else {
        // fp32 fallback (R1 structure)
        scan_kernel<<<256, 64, 0, stream>>>(O, idx, right);
        gather_rows<<<1024, 512, 0, stream>>>(right, act, fw);
        gather_rows<<<1024, 512, 0, stream>>>(right, inact, mw);
        gemm_nt64<<<dim3(32, 32), 256, 0, stream>>>(right, NDIM, nullptr, A, NDIM, nullptr,
                                                    A_rec, NDIM, NDIM);
        diag_kernel<<<2048, 256, 0, stream>>>(A_rec, right, diag_all);
        prep2_kernel<<<1, 1024, 0, stream>>>(act, inact, diag_all, inva, dm, dmrow);
        gemm_nt64<<<dim3(16, 16), 256, 0, stream>>>(A_rec, NDIM, act, right, NDIM, act,
                                                    fc, HALF, NDIM);
        gemm_nn64<<<dim3(16, 32), 256, 0, stream>>>(fc, HALF, fw, NDIM, D, NDIM, HALF);
        arec64<<<dim3(32, 32), 256, 0, stream>>>(fw, mw, D, dm, A_rec);
        build_D<<<16384, 256, 0, stream>>>(fc, diag_all, inva, D);
        mc_kernel<<<4096, 256, 0, stream>>>(dm, mc);
    }
}

// Round 6
// 567.844 us; speedup vs baseline: 1.4451x; 1.2094x over previous
//
#include <hip/hip_runtime.h>

// Problem constants (N=2048, L=512, K=16, DROP=2, DIM=1024)
#define NDIM 2048
#define LLEV 512
#define KDIM 16
#define HALF 1024

typedef __attribute__((ext_vector_type(8))) short bf16x8;   // 8 bf16 = 4 VGPRs
typedef __attribute__((ext_vector_type(4))) float f32x4;

// ---------------------------------------------------------------------------
// bf16 split helpers: x ~= hi + lo, each RNE bf16 (~16-17 mantissa bits total)
// ---------------------------------------------------------------------------
__device__ inline unsigned short f2bf(float x) {
    unsigned u = __float_as_uint(x);
    u += 0x7fffu + ((u >> 16) & 1u);
    return (unsigned short)(u >> 16);
}
__device__ inline float bf2f(unsigned short b) {
    return __uint_as_float(((unsigned)b) << 16);
}
__device__ inline void split2(float x, unsigned short& h, unsigned short& l) {
    h = f2bf(x);
    l = f2bf(x - bf2f(h));
}

__device__ inline void gl2lds16(const void* g, void* l) {
    __builtin_amdgcn_global_load_lds(
        (const __attribute__((address_space(1))) void*)g,
        (__attribute__((address_space(3))) void*)l, 16, 0, 0);
}

// ---------------------------------------------------------------------------
// compose_kernel: pairwise level composition (validated R4/R5).
// ---------------------------------------------------------------------------
__global__ __launch_bounds__(64) void compose_kernel(const float* __restrict__ O,
                                                     const int* __restrict__ idx,
                                                     int* __restrict__ Sarr,
                                                     float* __restrict__ Warr)
{
    __shared__ int s_S[32];
    __shared__ int s_pos[32];
    __shared__ float s_W[32][33];
    const int t = blockIdx.x;
    const int lane = threadIdx.x;
    const int* a = idx + (2 * t) * 16;
    const int* b = idx + (2 * t + 1) * 16;

    if (lane == 0) {
        int na = 0, i = 0, j = 0;
        while (i < 16 || j < 16) {
            int va = (i < 16) ? a[i] : 0x7fffffff;
            int vb = (j < 16) ? b[j] : 0x7fffffff;
            int v = va < vb ? va : vb;
            if (va == v) i++;
            if (vb == v) j++;
            s_S[na++] = v;
        }
        const int nm = na;
        int r = 0, p = 0;
        while (na < 32) {
            while (p < nm && s_S[p] < r) p++;
            if (p < nm && s_S[p] == r) { r++; continue; }
            s_S[na++] = r++;
        }
    }
    __syncthreads();
    if (lane < 32) {
        const int v = (lane < 16) ? a[lane] : b[lane - 16];
        int pp = 0;
        #pragma unroll
        for (int q = 0; q < 32; ++q) if (s_S[q] == v) pp = q;
        s_pos[lane] = pp;
        #pragma unroll
        for (int c = 0; c < 33; ++c) s_W[lane][c] = 0.f;
        s_W[lane][lane] = 1.f;
    }
    __syncthreads();
    const int j  = lane >> 2;
    const int cg = (lane & 3) * 8;
    #pragma unroll
    for (int step = 0; step < 2; ++step) {
        const float* Om = O + (size_t)(2 * t + step) * 256;
        float acc[8] = {};
        for (int k = 0; k < 16; ++k) {
            const float o = Om[j * 16 + k];
            const int p = s_pos[step * 16 + k];
            #pragma unroll
            for (int c = 0; c < 8; ++c) acc[c] += o * s_W[p][cg + c];
        }
        __syncthreads();
        const int pj = s_pos[step * 16 + j];
        #pragma unroll
        for (int c = 0; c < 8; ++c) s_W[pj][cg + c] = acc[c];
        __syncthreads();
    }
    if (lane < 32) Sarr[t * 32 + lane] = s_S[lane];
    {
        const int r = lane >> 1, h0 = (lane & 1) * 16;
        float* wp = Warr + (size_t)t * 1024 + r * 32 + h0;
        #pragma unroll
        for (int c = 0; c < 16; ++c) wp[c] = s_W[r][h0 + c];
    }
}

// ---------------------------------------------------------------------------
// scan3_kernel: batch-2 scan with k-split lanes (validated R5).
// ---------------------------------------------------------------------------
__global__ __launch_bounds__(64) void scan3_kernel(const float* __restrict__ Warr,
                                                   const int* __restrict__ Sarr,
                                                   float* __restrict__ right)
{
    __shared__ float slab[NDIM * 4];
    const int lane = threadIdx.x;
    const int c0 = blockIdx.x * 4;
    const int rr = lane & 31;
    const int ks = lane >> 5;

    for (int r = lane; r < NDIM; r += 64)
        *(float4*)&slab[r * 4] = make_float4(0.f, 0.f, 0.f, 0.f);
    if (lane < 4) slab[(c0 + lane) * 4 + lane] = 1.0f;

    int rows[16]; float cf[16]; int wrow;
    {
        const int4* sp = (const int4*)(Sarr + ks * 16);
        #pragma unroll
        for (int q = 0; q < 4; ++q) *(int4*)&rows[q * 4] = sp[q];
        const float4* wp = (const float4*)(Warr + rr * 32 + ks * 16);
        #pragma unroll
        for (int q = 0; q < 4; ++q) *(float4*)&cf[q * 4] = wp[q];
        wrow = Sarr[rr];
    }

    for (int t = 0; t < 256; ++t) {
        int cr[16]; float cc[16];
        const int wr = wrow;
        #pragma unroll
        for (int q = 0; q < 16; ++q) { cr[q] = rows[q]; cc[q] = cf[q]; }
        if (t + 1 < 256) {
            const int4* sp = (const int4*)(Sarr + (t + 1) * 32 + ks * 16);
            #pragma unroll
            for (int q = 0; q < 4; ++q) *(int4*)&rows[q * 4] = sp[q];
            const float4* wp = (const float4*)(Warr + (size_t)(t + 1) * 1024 + rr * 32 + ks * 16);
            #pragma unroll
            for (int q = 0; q < 4; ++q) *(float4*)&cf[q * 4] = wp[q];
            wrow = Sarr[(t + 1) * 32 + rr];
        }
        float4 acc = make_float4(0.f, 0.f, 0.f, 0.f);
        #pragma unroll
        for (int j = 0; j < 16; ++j) {
            float4 v = *(const float4*)&slab[cr[j] * 4];
            acc.x += cc[j] * v.x; acc.y += cc[j] * v.y;
            acc.z += cc[j] * v.z; acc.w += cc[j] * v.w;
        }
        acc.x += __shfl_xor(acc.x, 32, 64);
        acc.y += __shfl_xor(acc.y, 32, 64);
        acc.z += __shfl_xor(acc.z, 32, 64);
        acc.w += __shfl_xor(acc.w, 32, 64);
        if (lane < 32)
            *(float4*)&slab[wr * 4] = acc;
    }

    #pragma unroll 4
    for (int i = 0; i < 32; ++i) {
        const int r = i * 64 + lane;
        *(float4*)(right + (size_t)r * NDIM + c0) = *(float4*)&slab[r * 4];
    }
}

// ---------------------------------------------------------------------------
// Old scan (fp32 fallback path only)
// ---------------------------------------------------------------------------
__global__ __launch_bounds__(64) void scan_kernel(const float* __restrict__ O,
                                                  const int* __restrict__ idx,
                                                  float* __restrict__ right)
{
    __shared__ float slab[NDIM * 8];
    const int lane = threadIdx.x;
    const int c0 = blockIdx.x * 8;
    const int k  = lane >> 2;
    const int c2 = (lane & 3) * 2;

    for (int r = lane; r < NDIM; r += 64) {
        *(float4*)&slab[r * 8]     = make_float4(0.f, 0.f, 0.f, 0.f);
        *(float4*)&slab[r * 8 + 4] = make_float4(0.f, 0.f, 0.f, 0.f);
    }
    if (lane < 8) slab[(c0 + lane) * 8 + lane] = 1.0f;

    int rows[16]; float a[16]; int wrow;
    #pragma unroll
    for (int j = 0; j < 16; ++j) rows[j] = idx[j];
    {
        const float4* p4 = (const float4*)(O + k * 16);
        #pragma unroll
        for (int q = 0; q < 4; ++q) *(float4*)&a[q * 4] = p4[q];
    }
    wrow = idx[k];

    for (int l = 0; l < LLEV; ++l) {
        int rr[16]; float aa[16];
        const int wr = wrow;
        #pragma unroll
        for (int j = 0; j < 16; ++j) { rr[j] = rows[j]; aa[j] = a[j]; }
        if (l + 1 < LLEV) {
            const int* ip = idx + (l + 1) * 16;
            #pragma unroll
            for (int j = 0; j < 16; ++j) rows[j] = ip[j];
            const float4* p4 = (const float4*)(O + (l + 1) * 256 + k * 16);
            #pragma unroll
            for (int q = 0; q < 4; ++q) *(float4*)&a[q * 4] = p4[q];
            wrow = ip[k];
        }
        float sx = 0.f, sy = 0.f;
        #pragma unroll
        for (int j = 0; j < 16; ++j) {
            float2 v = *(float2*)&slab[rr[j] * 8 + c2];
            sx += aa[j] * v.x;
            sy += aa[j] * v.y;
        }
        *(float2*)&slab[wr * 8 + c2] = make_float2(sx, sy);
    }

    for (int r0 = 0; r0 < NDIM; r0 += 32) {
        const int r = r0 + (lane >> 1);
        const int h = (lane & 1) * 4;
        *(float4*)(right + (size_t)r * NDIM + c0 + h) = *(float4*)&slab[r * 8 + h];
    }
}

// ---------------------------------------------------------------------------
// Split-bf16 MFMA NT gemm with SPLIT-K: blockIdx.z owns K-slice
// [z*K/ksplit, (z+1)*K/ksplit), writes partial to C + z*strideZ.
// 3-pass hi/lo, 128x128 tile, BK=64. (R5 structure + z-split for occupancy:
// grid was 256 blocks = 1 block/CU -> barrier drains un-hidden.)
// ---------------------------------------------------------------------------
#define GBK 64
__global__ __launch_bounds__(256) void mfma_nt(const unsigned short* __restrict__ Ah,
                                               const unsigned short* __restrict__ Al,
                                               const unsigned short* __restrict__ Bh,
                                               const unsigned short* __restrict__ Bl,
                                               float* __restrict__ C,
                                               long strideZ,
                                               int M, int N, int K, int ksplit)
{
    __shared__ unsigned short sA_h[8 * 128 * 8];
    __shared__ unsigned short sA_l[8 * 128 * 8];
    __shared__ unsigned short sB_h[8 * 128 * 8];
    __shared__ unsigned short sB_l[8 * 128 * 8];

    const int tid  = threadIdx.x;
    const int wave = tid >> 6, lane = tid & 63;
    const int lm   = lane & 15, quad = lane >> 4;
    const int wm   = wave & 1,  wn   = wave >> 1;
    const int m0   = blockIdx.x * 128, n0 = blockIdx.y * 128;
    const int Kz   = K / ksplit;
    const int kbeg = Kz * blockIdx.z;
    C += (size_t)blockIdx.z * strideZ;

    const unsigned short* gbase;
    unsigned short* sbase;
    if      (wave == 0) { gbase = Ah + (size_t)m0 * K; sbase = sA_h; }
    else if (wave == 1) { gbase = Al + (size_t)m0 * K; sbase = sA_l; }
    else if (wave == 2) { gbase = Bh + (size_t)n0 * K; sbase = sB_h; }
    else                { gbase = Bl + (size_t)n0 * K; sbase = sB_l; }

    f32x4 acc[4][4];
    #pragma unroll
    for (int i = 0; i < 4; ++i)
        #pragma unroll
        for (int j = 0; j < 4; ++j) acc[i][j] = (f32x4){0.f, 0.f, 0.f, 0.f};

    for (int k0 = kbeg; k0 < kbeg + Kz; k0 += GBK) {
        #pragma unroll
        for (int h = 0; h < 2; ++h) {
            const unsigned short* gr = gbase + (size_t)(h * 64 + lane) * K + k0;
            unsigned short* sb = sbase + h * 512;
            #pragma unroll
            for (int c = 0; c < 8; ++c)
                gl2lds16(gr + c * 8, sb + c * 1024);
        }
        __syncthreads();
        #pragma unroll
        for (int sub = 0; sub < 2; ++sub) {
            const int co = (sub * 4 + quad) * 1024;
            bf16x8 ah[4], al[4], bh[4], bl[4];
            #pragma unroll
            for (int i = 0; i < 4; ++i) {
                const int m = wm * 64 + i * 16 + lm;
                ah[i] = *(const bf16x8*)&sA_h[co + m * 8];
                al[i] = *(const bf16x8*)&sA_l[co + m * 8];
            }
            #pragma unroll
            for (int j = 0; j < 4; ++j) {
                const int n = wn * 64 + j * 16 + lm;
                bh[j] = *(const bf16x8*)&sB_h[co + n * 8];
                bl[j] = *(const bf16x8*)&sB_l[co + n * 8];
            }
            #pragma unroll
            for (int i = 0; i < 4; ++i)
                #pragma unroll
                for (int j = 0; j < 4; ++j) {
                    acc[i][j] = __builtin_amdgcn_mfma_f32_16x16x32_bf16(ah[i], bh[j], acc[i][j], 0, 0, 0);
                    acc[i][j] = __builtin_amdgcn_mfma_f32_16x16x32_bf16(ah[i], bl[j], acc[i][j], 0, 0, 0);
                    acc[i][j] = __builtin_amdgcn_mfma_f32_16x16x32_bf16(al[i], bh[j], acc[i][j], 0, 0, 0);
                }
        }
        __syncthreads();
    }
    #pragma unroll
    for (int i = 0; i < 4; ++i) {
        const int mrow = m0 + wm * 64 + i * 16 + quad * 4;
        #pragma unroll
        for (int j = 0; j < 4; ++j) {
            float* cp = C + (size_t)mrow * N + n0 + wn * 64 + j * 16 + lm;
            #pragma unroll
            for (int r = 0; r < 4; ++r) cp[(size_t)r * N] = acc[i][j][r];
        }
    }
}

// ---------------------------------------------------------------------------
// reduce_k: dst[i] = sum_z parts[i + z*strideZ], float4 per thread.
// (dst may alias parts' z=0 slice — each thread owns its own i.)
// ---------------------------------------------------------------------------
__global__ __launch_bounds__(256) void reduce_k(float* __restrict__ dst,
                                                const float* __restrict__ parts,
                                                long strideZ, int nz, long n)
{
    const long i = ((long)blockIdx.x * 256 + threadIdx.x) * 4;
    if (i >= n) return;
    float4 s = *(const float4*)(parts + i);
    for (int z = 1; z < nz; ++z) {
        float4 v = *(const float4*)(parts + (size_t)z * strideZ + i);
        s.x += v.x; s.y += v.y; s.z += v.z; s.w += v.w;
    }
    *(float4*)(dst + i) = s;
}

// ---------------------------------------------------------------------------
// fp32 -> bf16 hi/lo conversion (optional row gather). 4 floats/thread.
// ---------------------------------------------------------------------------
__global__ __launch_bounds__(256) void conv_hl(const float* __restrict__ src,
                                               const int* __restrict__ gidx,
                                               int kshift,
                                               unsigned short* __restrict__ h,
                                               unsigned short* __restrict__ l)
{
    const long e = ((long)blockIdx.x * 256 + threadIdx.x) * 4;
    const float* s;
    if (gidx) {
        const long row = e >> kshift;
        const long col = e - (row << kshift);
        s = src + ((size_t)gidx[row] << kshift) + col;
    } else {
        s = src + e;
    }
    float4 v = *(const float4*)s;
    ushort4 hh, ll;
    split2(v.x, hh.x, ll.x); split2(v.y, hh.y, ll.y);
    split2(v.z, hh.z, ll.z); split2(v.w, hh.w, ll.w);
    *(ushort4*)(h + e) = hh;
    *(ushort4*)(l + e) = ll;
}

// ---------------------------------------------------------------------------
// Transposing fp32 -> bf16 hi/lo: dst[k][m] = src[m][k]. 64x64 LDS tile.
// ---------------------------------------------------------------------------
__global__ __launch_bounds__(256) void tconv_hl(const float* __restrict__ src,
                                                int Msrc, int Ksrc,
                                                unsigned short* __restrict__ h,
                                                unsigned short* __restrict__ l)
{
    __shared__ float t[64][65];
    const int bi = blockIdx.x, bj = blockIdx.y;
    const int tx = threadIdx.x & 15, ty = threadIdx.x >> 4;
    #pragma unroll
    for (int r = 0; r < 4; ++r) {
        const int row = bi * 64 + ty + r * 16;
        float4 v = *(const float4*)(src + (size_t)row * Ksrc + bj * 64 + tx * 4);
        t[ty + r * 16][tx * 4 + 0] = v.x; t[ty + r * 16][tx * 4 + 1] = v.y;
        t[ty + r * 16][tx * 4 + 2] = v.z; t[ty + r * 16][tx * 4 + 3] = v.w;
    }
    __syncthreads();
    #pragma unroll
    for (int r = 0; r < 4; ++r) {
        const int drow = bj * 64 + ty + r * 16;
        ushort4 hh, ll;
        split2(t[tx * 4 + 0][ty + r * 16], hh.x, ll.x);
        split2(t[tx * 4 + 1][ty + r * 16], hh.y, ll.y);
        split2(t[tx * 4 + 2][ty + r * 16], hh.z, ll.z);
        split2(t[tx * 4 + 3][ty + r * 16], hh.w, ll.w);
        *(ushort4*)(h + (size_t)drow * Msrc + bi * 64 + tx * 4) = hh;
        *(ushort4*)(l + (size_t)drow * Msrc + bi * 64 + tx * 4) = ll;
    }
}

// ---------------------------------------------------------------------------
// GT[n,r] = Gfull[r,n] transposed+converted, Gfull fused on the fly.
// ---------------------------------------------------------------------------
__global__ __launch_bounds__(256) void gt_build(const float* __restrict__ W1,
                                                const float* __restrict__ right,
                                                const int* __restrict__ inva,
                                                const float* __restrict__ dmrow,
                                                unsigned short* __restrict__ h,
                                                unsigned short* __restrict__ l)
{
    __shared__ float t[64][65];
    const int bi = blockIdx.x, bj = blockIdx.y;
    const int tx = threadIdx.x & 15, ty = threadIdx.x >> 4;
    #pragma unroll
    for (int rr = 0; rr < 4; ++rr) {
        const int r = bi * 64 + ty + rr * 16;
        const int ia = inva[r];
        float4 v;
        if (ia >= 0) {
            v = *(const float4*)(W1 + (size_t)ia * NDIM + bj * 64 + tx * 4);
        } else {
            v = *(const float4*)(right + (size_t)r * NDIM + bj * 64 + tx * 4);
            const float s = dmrow[r];
            v.x *= s; v.y *= s; v.z *= s; v.w *= s;
        }
        t[ty + rr * 16][tx * 4 + 0] = v.x; t[ty + rr * 16][tx * 4 + 1] = v.y;
        t[ty + rr * 16][tx * 4 + 2] = v.z; t[ty + rr * 16][tx * 4 + 3] = v.w;
    }
    __syncthreads();
    #pragma unroll
    for (int rr = 0; rr < 4; ++rr) {
        const int drow = bj * 64 + ty + rr * 16;
        ushort4 hh, ll;
        split2(t[tx * 4 + 0][ty + rr * 16], hh.x, ll.x);
        split2(t[tx * 4 + 1][ty + rr * 16], hh.y, ll.y);
        split2(t[tx * 4 + 2][ty + rr * 16], hh.z, ll.z);
        split2(t[tx * 4 + 3][ty + rr * 16], hh.w, ll.w);
        *(ushort4*)(h + (size_t)drow * NDIM + bi * 64 + tx * 4) = hh;
        *(ushort4*)(l + (size_t)drow * NDIM + bi * 64 + tx * 4) = ll;
    }
}

// ---------------------------------------------------------------------------
// Small helpers
// ---------------------------------------------------------------------------
__global__ __launch_bounds__(256) void diag_kernel(const float* __restrict__ P,
                                                   const float* __restrict__ R,
                                                   float* __restrict__ diag_all)
{
    __shared__ float red[256];
    const int i = blockIdx.x;
    const float4* p4 = (const float4*)(P + (size_t)i * NDIM);
    const float4* r4 = (const float4*)(R + (size_t)i * NDIM);
    float s = 0.f;
    for (int kq = threadIdx.x; kq < NDIM / 4; kq += 256) {
        float4 a = p4[kq], b = r4[kq];
        s += a.x * b.x + a.y * b.y + a.z * b.z + a.w * b.w;
    }
    red[threadIdx.x] = s;
    __syncthreads();
    for (int off = 128; off > 0; off >>= 1) {
        if (threadIdx.x < off) red[threadIdx.x] += red[threadIdx.x + off];
        __syncthreads();
    }
    if (threadIdx.x == 0) diag_all[i] = red[0];
}

__global__ void prep2_kernel(const int* __restrict__ act, const int* __restrict__ inact,
                             const float* __restrict__ diag_all,
                             int* __restrict__ inva, float* __restrict__ dm,
                             float* __restrict__ dmrow)
{
    const int t = threadIdx.x;
    inva[t] = -1;
    inva[t + HALF] = -1;
    __syncthreads();
    inva[act[t]] = t;
    const int ir = inact[t];
    const float dv = diag_all[ir];
    dm[t] = dv;
    dmrow[ir] = dv;
}

__global__ __launch_bounds__(256) void build_D(const float* __restrict__ Daa,
                                               const float* __restrict__ diag_all,
                                               const int* __restrict__ inva,
                                               float* __restrict__ D)
{
    const int e = blockIdx.x * 256 + threadIdx.x;
    const int i = e >> 11, j = e & (NDIM - 1);
    const int ii = inva[i], jj = inva[j];
    float v = 0.f;
    if (ii >= 0 && jj >= 0) v = Daa[ii * HALF + jj];
    if (i == j) v = diag_all[i];
    D[e] = v;
}

__global__ __launch_bounds__(256) void mc_kernel(const float* __restrict__ dm,
                                                 float* __restrict__ mc)
{
    const int e = blockIdx.x * 256 + threadIdx.x;
    const int t = e >> 10, s = e & (HALF - 1);
    mc[e] = (t == s) ? dm[t] : 0.f;
}

__global__ __launch_bounds__(512) void gather_rows(const float* __restrict__ R,
                                                   const int* __restrict__ ridx,
                                                   float* __restrict__ outp)
{
    const int r = blockIdx.x;
    const int c = threadIdx.x * 4;
    *(float4*)(outp + (size_t)r * NDIM + c) =
        *(const float4*)(R + (size_t)ridx[r] * NDIM + c);
}

// ---------------------------------------------------------------------------
// fp32 fallback gemms (only if ws_size too small for bf16 scratch)
// ---------------------------------------------------------------------------
__global__ __launch_bounds__(256) void gemm_nt64(const float* __restrict__ A, int lda,
                                                 const int* __restrict__ ridxA,
                                                 const float* __restrict__ B, int ldb,
                                                 const int* __restrict__ ridxB,
                                                 float* __restrict__ C, int ldc, int Kk)
{
    __shared__ float As[16][68];
    __shared__ float Bs[16][68];
    const int tid = threadIdx.x;
    const int tx = tid & 15, ty = tid >> 4;
    const int m0 = blockIdx.x * 64, n0 = blockIdx.y * 64;
    const int li = tid >> 2;
    const int lk = (tid & 3) * 4;
    int rowA = m0 + li; if (ridxA) rowA = ridxA[rowA];
    int rowB = n0 + li; if (ridxB) rowB = ridxB[rowB];
    const float* pA = A + (size_t)rowA * lda + lk;
    const float* pB = B + (size_t)rowB * ldb + lk;
    float acc[4][4] = {};
    for (int k0 = 0; k0 < Kk; k0 += 16) {
        float4 a4 = *(const float4*)(pA + k0);
        float4 b4 = *(const float4*)(pB + k0);
        As[lk + 0][li] = a4.x; As[lk + 1][li] = a4.y; As[lk + 2][li] = a4.z; As[lk + 3][li] = a4.w;
        Bs[lk + 0][li] = b4.x; Bs[lk + 1][li] = b4.y; Bs[lk + 2][li] = b4.z; Bs[lk + 3][li] = b4.w;
        __syncthreads();
        #pragma unroll
        for (int kk = 0; kk < 16; ++kk) {
            float4 av = *(const float4*)&As[kk][ty * 4];
            float4 bv = *(const float4*)&Bs[kk][tx * 4];
            float a[4] = {av.x, av.y, av.z, av.w};
            float b[4] = {bv.x, bv.y, bv.z, bv.w};
            #pragma unroll
            for (int i = 0; i < 4; ++i)
                #pragma unroll
                for (int j = 0; j < 4; ++j) acc[i][j] += a[i] * b[j];
        }
        __syncthreads();
    }
    #pragma unroll
    for (int i = 0; i < 4; ++i) {
        float4 v = make_float4(acc[i][0], acc[i][1], acc[i][2], acc[i][3]);
        *(float4*)(C + (size_t)(m0 + ty * 4 + i) * ldc + n0 + tx * 4) = v;
    }
}

__global__ __launch_bounds__(256) void gemm_nn64(const float* __restrict__ A, int lda,
                                                 const float* __restrict__ B, int ldb,
                                                 float* __restrict__ C, int ldc, int Kk)
{
    __shared__ float As[16][68];
    __shared__ float Bs[16][68];
    const int tid = threadIdx.x;
    const int tx = tid & 15, ty = tid >> 4;
    const int m0 = blockIdx.x * 64, n0 = blockIdx.y * 64;
    const int li = tid >> 2;
    const int lk = (tid & 3) * 4;
    const int bk = tid >> 4;
    const int bn = (tid & 15) * 4;
    const float* pA = A + (size_t)(m0 + li) * lda + lk;
    float acc[4][4] = {};
    for (int k0 = 0; k0 < Kk; k0 += 16) {
        float4 a4 = *(const float4*)(pA + k0);
        float4 b4 = *(const float4*)(B + (size_t)(k0 + bk) * ldb + n0 + bn);
        As[lk + 0][li] = a4.x; As[lk + 1][li] = a4.y; As[lk + 2][li] = a4.z; As[lk + 3][li] = a4.w;
        *(float4*)&Bs[bk][bn] = b4;
        __syncthreads();
        #pragma unroll
        for (int kk = 0; kk < 16; ++kk) {
            float4 av = *(const float4*)&As[kk][ty * 4];
            float4 bv = *(const float4*)&Bs[kk][tx * 4];
            float a[4] = {av.x, av.y, av.z, av.w};
            float b[4] = {bv.x, bv.y, bv.z, bv.w};
            #pragma unroll
            for (int i = 0; i < 4; ++i)
                #pragma unroll
                for (int j = 0; j < 4; ++j) acc[i][j] += a[i] * b[j];
        }
        __syncthreads();
    }
    #pragma unroll
    for (int i = 0; i < 4; ++i) {
        float4 v = make_float4(acc[i][0], acc[i][1], acc[i][2], acc[i][3]);
        *(float4*)(C + (size_t)(m0 + ty * 4 + i) * ldc + n0 + tx * 4) = v;
    }
}

__global__ __launch_bounds__(256) void arec64(const float* __restrict__ fw,
                                              const float* __restrict__ mw,
                                              const float* __restrict__ W1,
                                              const float* __restrict__ dm,
                                              float* __restrict__ C)
{
    __shared__ float As[16][68];
    __shared__ float Bs[16][68];
    const int tid = threadIdx.x;
    const int tx = tid & 15, ty = tid >> 4;
    const int m0 = blockIdx.x * 64, n0 = blockIdx.y * 64;
    const int bk = tid >> 4;
    const int bn = (tid & 15) * 4;
    float acc[4][4] = {};
    for (int t0 = 0; t0 < NDIM; t0 += 16) {
        const int t = t0 + bk;
        const float* Hrow; const float* Grow; float gs;
        if (t < HALF) { Hrow = fw + (size_t)t * NDIM; Grow = W1 + (size_t)t * NDIM; gs = 1.f; }
        else          { Hrow = mw + (size_t)(t - HALF) * NDIM; Grow = Hrow; gs = dm[t - HALF]; }
        float4 a4 = *(const float4*)(Hrow + m0 + bn);
        float4 b4 = *(const float4*)(Grow + n0 + bn);
        b4.x *= gs; b4.y *= gs; b4.z *= gs; b4.w *= gs;
        *(float4*)&As[bk][bn] = a4;
        *(float4*)&Bs[bk][bn] = b4;
        __syncthreads();
        #pragma unroll
        for (int kk = 0; kk < 16; ++kk) {
            float4 av = *(const float4*)&As[kk][ty * 4];
            float4 bv = *(const float4*)&Bs[kk][tx * 4];
            float a[4] = {av.x, av.y, av.z, av.w};
            float b[4] = {bv.x, bv.y, bv.z, bv.w};
            #pragma unroll
            for (int i = 0; i < 4; ++i)
                #pragma unroll
                for (int j = 0; j < 4; ++j) acc[i][j] += a[i] * b[j];
        }
        __syncthreads();
    }
    #pragma unroll
    for (int i = 0; i < 4; ++i) {
        float4 v = make_float4(acc[i][0], acc[i][1], acc[i][2], acc[i][3]);
        *(float4*)(C + (size_t)(m0 + ty * 4 + i) * NDIM + n0 + tx * 4) = v;
    }
}

// ---------------------------------------------------------------------------
extern "C" void kernel_launch(void* const* d_in, const int* in_sizes, int n_in,
                              void* d_out, int out_size, void* d_ws, size_t ws_size,
                              hipStream_t stream)
{
    (void)in_sizes; (void)n_in; (void)out_size;
    const float* A     = (const float*)d_in[0];
    const float* O     = (const float*)d_in[1];
    const int*   idx   = (const int*)d_in[2];
    const int*   act   = (const int*)d_in[3];
    const int*   inact = (const int*)d_in[4];

    float* out = (float*)d_out;
    const size_t NN = (size_t)NDIM * NDIM;
    float* A_rec = out;                       // scratch for P until final gemm
    float* right = out + NN;
    float* D     = out + 2 * NN;              // scratch: split-K partials / W1
    float* mc    = out + 3 * NN;
    float* fc    = mc + (size_t)HALF * HALF;  // Daa
    float* mw    = fc + (size_t)HALF * HALF;
    float* fw    = mw + (size_t)HALF * NDIM;

    char*  w        = (char*)d_ws;
    float* diag_all = (float*)w;              // 2048 f
    float* dm       = (float*)(w + 8192);     // 1024 f
    int*   inva     = (int*)(w + 12288);      // 2048 i
    float* dmrow    = (float*)(w + 20480);    // 2048 f

    const size_t MB = 1024 * 1024;
    const size_t WS_NEEDED = 65536 + 32 * MB;

    if (ws_size >= WS_NEEDED) {
        char* r1 = w + 65536;                 // 16 MB: (Warr/Sarr) -> Rh/Rl -> RTh/RTl
        char* r2 = r1 + 16 * MB;              // 16 MB: Ah/Al -> Pa/F -> D/FT -> GT
        float* Warr = (float*)r1;             // 1 MB (consumed by scan3)
        int*   Sarr = (int*)(r1 + MB);        // 32 KB
        unsigned short* Rh  = (unsigned short*)r1;
        unsigned short* Rl  = (unsigned short*)(r1 + 8 * MB);
        unsigned short* RTh = Rh;
        unsigned short* RTl = Rl;
        unsigned short* Ah  = (unsigned short*)r2;
        unsigned short* Al  = (unsigned short*)(r2 + 8 * MB);
        unsigned short* Pah = (unsigned short*)r2;             // after P
        unsigned short* Pal = (unsigned short*)(r2 + 4 * MB);
        unsigned short* Fh  = (unsigned short*)(r2 + 8 * MB);
        unsigned short* Fl  = (unsigned short*)(r2 + 12 * MB);
        unsigned short* Dh  = (unsigned short*)r2;             // after Daa
        unsigned short* Dl  = (unsigned short*)(r2 + 2 * MB);
        unsigned short* FTh = (unsigned short*)(r2 + 4 * MB);
        unsigned short* FTl = (unsigned short*)(r2 + 8 * MB);
        unsigned short* GTh = (unsigned short*)r2;             // after W1
        unsigned short* GTl = (unsigned short*)(r2 + 8 * MB);

        // 1. pairwise level composition, then 256-level k-split scan
        compose_kernel<<<256, 64, 0, stream>>>(O, idx, Sarr, Warr);
        scan3_kernel<<<512, 64, 0, stream>>>(Warr, Sarr, right);
        // 2. wavelets
        gather_rows<<<1024, 512, 0, stream>>>(right, act, fw);
        gather_rows<<<1024, 512, 0, stream>>>(right, inact, mw);
        // 3. convert R and A to bf16 hi/lo (overwrites Warr/Sarr — consumed)
        conv_hl<<<4096, 256, 0, stream>>>(right, nullptr, 11, Rh, Rl);
        conv_hl<<<4096, 256, 0, stream>>>(A, nullptr, 11, Ah, Al);
        // 4. P = R @ A, split-K=2: z0 -> A_rec, z1 -> D slot; reduce into A_rec
        mfma_nt<<<dim3(16, 16, 2), 256, 0, stream>>>(Rh, Rl, Ah, Al, A_rec,
                                                     (long)2 * NN, NDIM, NDIM, NDIM, 2);
        reduce_k<<<4096, 256, 0, stream>>>(A_rec, A_rec, (long)2 * NN, 2, (long)NN);
        // 5. diag + prep
        diag_kernel<<<2048, 256, 0, stream>>>(A_rec, right, diag_all);
        prep2_kernel<<<1, 1024, 0, stream>>>(act, inact, diag_all, inva, dm, dmrow);
        // 7. Pa = P[act], F = fw in bf16
        conv_hl<<<2048, 256, 0, stream>>>(A_rec, act, 11, Pah, Pal);
        conv_hl<<<2048, 256, 0, stream>>>(fw, nullptr, 11, Fh, Fl);
        // 8. Daa = Pa . F^T, split-K=4: partials in D slot (4 x 4 MB); reduce -> fc
        mfma_nt<<<dim3(8, 8, 4), 256, 0, stream>>>(Pah, Pal, Fh, Fl, D,
                                                   (long)HALF * HALF, HALF, HALF, NDIM, 4);
        reduce_k<<<1024, 256, 0, stream>>>(fc, D, (long)HALF * HALF, 4, (long)HALF * HALF);
        // 9. Dh/Dl = conv(Daa); FT = fw^T
        conv_hl<<<1024, 256, 0, stream>>>(fc, nullptr, 10, Dh, Dl);
        tconv_hl<<<dim3(16, 32), 256, 0, stream>>>(fw, HALF, NDIM, FTh, FTl);
        // 10. W1 = Daa @ fw, split-K=2: z0 -> D (final home), z1 -> D+8MB; reduce
        mfma_nt<<<dim3(8, 16, 2), 256, 0, stream>>>(Dh, Dl, FTh, FTl, D,
                                                    (long)HALF * NDIM, HALF, NDIM, HALF, 2);
        reduce_k<<<2048, 256, 0, stream>>>(D, D, (long)HALF * NDIM, 2, (long)HALF * NDIM);
        // 11. RT = right^T
        tconv_hl<<<dim3(32, 32), 256, 0, stream>>>(right, NDIM, NDIM, RTh, RTl);
        // 12. GT from W1 / dm*right (consumes W1 in D slot)
        gt_build<<<dim3(32, 32), 256, 0, stream>>>(D, right, inva, dmrow, GTh, GTl);
        // 13. A_rec = RT . GT^T, split-K=2: z0 -> A_rec, z1 -> D slot; reduce
        mfma_nt<<<dim3(16, 16, 2), 256, 0, stream>>>(RTh, RTl, GTh, GTl, A_rec,
                                                     (long)2 * NN, NDIM, NDIM, NDIM, 2);
        reduce_k<<<4096, 256, 0, stream>>>(A_rec, A_rec, (long)2 * NN, 2, (long)NN);
        // 14. D output (overwrites partial scratch)
        build_D<<<16384, 256, 0, stream>>>(fc, diag_all, inva, D);
        // 15. mother_coefficients = diag(dm)
        mc_kernel<<<4096, 256, 0, stream>>>(dm, mc);
    } else {
        // fp32 fallback (R1 structure)
        scan_kernel<<<256, 64, 0, stream>>>(O, idx, right);
        gather_rows<<<1024, 512, 0, stream>>>(right, act, fw);
        gather_rows<<<1024, 512, 0, stream>>>(right, inact, mw);
        gemm_nt64<<<dim3(32, 32), 256, 0, stream>>>(right, NDIM, nullptr, A, NDIM, nullptr,
                                                    A_rec, NDIM, NDIM);
        diag_kernel<<<2048, 256, 0, stream>>>(A_rec, right, diag_all);
        prep2_kernel<<<1, 1024, 0, stream>>>(act, inact, diag_all, inva, dm, dmrow);
        gemm_nt64<<<dim3(16, 16), 256, 0, stream>>>(A_rec, NDIM, act, right, NDIM, act,
                                                    fc, HALF, NDIM);
        gemm_nn64<<<dim3(16, 32), 256, 0, stream>>>(fc, HALF, fw, NDIM, D, NDIM, HALF);
        arec64<<<dim3(32, 32), 256, 0, stream>>>(fw, mw, D, dm, A_rec);
        build_D<<<16384, 256, 0, stream>>>(fc, diag_all, inva, D);
        mc_kernel<<<4096, 256, 0, stream>>>(dm, mc);
    }
}